// Round 1
// baseline (1984.309 us; speedup 1.0000x reference)
//
#include <hip/hip_runtime.h>
#include <hip/hip_bf16.h>
#include <math.h>

// Problem constants
#define B_ 4
#define L_ 4096
#define E_ 1024
#define H_ 16
#define D_ 64
#define M_ (B_*L_)   // 16384 rows

// g(x) = (softplus(5x)/5)^2, numerically stable
__device__ __forceinline__ float gfun(float x) {
  float z = 5.0f * x;
  float sp = fmaxf(z, 0.0f) + log1pf(__expf(-fabsf(z)));
  sp *= 0.2f;
  return sp * sp;
}

// ---------------------------------------------------------------------------
// Kernel 1: fused QKV projection.  out = X @ W + b for W in {Wq,Wk,Wv}
// fp32 tiled GEMM: BM=BN=128, BK=8, 8x8 per thread, 256 threads.
// grid = (N/128, M/128, 3)
// ---------------------------------------------------------------------------
#define BM 128
#define BN 128
#define BK 8

__global__ __launch_bounds__(256) void qkv_gemm(
    const float* __restrict__ X,
    const float* __restrict__ Wq, const float* __restrict__ bq,
    const float* __restrict__ Wk, const float* __restrict__ bk,
    const float* __restrict__ Wv, const float* __restrict__ bv,
    float* __restrict__ qo, float* __restrict__ ko, float* __restrict__ vo)
{
  const float* W; const float* bias; float* out;
  if (blockIdx.z == 0)      { W = Wq; bias = bq; out = qo; }
  else if (blockIdx.z == 1) { W = Wk; bias = bk; out = ko; }
  else                      { W = Wv; bias = bv; out = vo; }

  __shared__ float As[BK][BM];   // A stored transposed: As[k][m]
  __shared__ float Bs[BK][BN];

  const int t    = threadIdx.x;
  const int brow = blockIdx.y * BM;
  const int bcol = blockIdx.x * BN;
  const int a_row = t >> 1;          // 0..127
  const int a_col = (t & 1) * 4;     // 0 or 4
  const int b_row = t >> 5;          // 0..7
  const int b_col = (t & 31) * 4;    // 0..124
  const int ty = t >> 4;             // 0..15
  const int tx = t & 15;             // 0..15

  const float* Ap  = X + (size_t)(brow + a_row) * E_ + a_col;
  const float* Bp0 = W + (size_t)b_row * E_ + bcol + b_col;

  float acc[8][8] = {};
  float4 a4 = *(const float4*)(Ap);
  float4 b4 = *(const float4*)(Bp0);

  for (int k0 = 0; k0 < E_; k0 += BK) {
    As[a_col+0][a_row] = a4.x;
    As[a_col+1][a_row] = a4.y;
    As[a_col+2][a_row] = a4.z;
    As[a_col+3][a_row] = a4.w;
    *(float4*)&Bs[b_row][b_col] = b4;
    __syncthreads();
    if (k0 + BK < E_) {            // prefetch next tile while computing
      a4 = *(const float4*)(Ap + k0 + BK);
      b4 = *(const float4*)(Bp0 + (size_t)(k0 + BK) * E_);
    }
    #pragma unroll
    for (int kk = 0; kk < BK; ++kk) {
      float a[8], bb[8];
      *(float4*)&a[0]  = *(float4*)&As[kk][ty*8];
      *(float4*)&a[4]  = *(float4*)&As[kk][ty*8+4];
      *(float4*)&bb[0] = *(float4*)&Bs[kk][tx*8];
      *(float4*)&bb[4] = *(float4*)&Bs[kk][tx*8+4];
      #pragma unroll
      for (int i = 0; i < 8; ++i)
        #pragma unroll
        for (int j = 0; j < 8; ++j)
          acc[i][j] = fmaf(a[i], bb[j], acc[i][j]);
    }
    __syncthreads();
  }

  float bcv[8];
  #pragma unroll
  for (int j = 0; j < 8; ++j) bcv[j] = bias[bcol + tx*8 + j];
  #pragma unroll
  for (int i = 0; i < 8; ++i) {
    float4 r0, r1;
    r0.x = acc[i][0]+bcv[0]; r0.y = acc[i][1]+bcv[1];
    r0.z = acc[i][2]+bcv[2]; r0.w = acc[i][3]+bcv[3];
    r1.x = acc[i][4]+bcv[4]; r1.y = acc[i][5]+bcv[5];
    r1.z = acc[i][6]+bcv[6]; r1.w = acc[i][7]+bcv[7];
    size_t ro = (size_t)(brow + ty*8 + i) * E_ + bcol + tx*8;
    *(float4*)(out + ro)     = r0;
    *(float4*)(out + ro + 4) = r1;
  }
}

// ---------------------------------------------------------------------------
// Kernel 2: q_global[b,h,d] = mean_l q[b,l,h,d] / sqrt(D)
// grid = (B*H, 4 chunks); atomic partial sums into zeroed qg.
// ---------------------------------------------------------------------------
__global__ __launch_bounds__(256) void qglobal_kernel(
    const float* __restrict__ q, float* __restrict__ qg)
{
  int bh = blockIdx.x;            // 0..63
  int b = bh >> 4, h = bh & 15;
  int t = threadIdx.x;
  int d = t & 63, c = t >> 6;     // 4 sub-chunks of 256 l's
  int l0 = blockIdx.y * 1024 + c * 256;
  const float* base = q + (size_t)(b * L_ + l0) * E_ + h * 64 + d;
  float s = 0.f;
  #pragma unroll 8
  for (int i = 0; i < 256; ++i) s += base[(size_t)i * E_];
  __shared__ float red[256];
  red[t] = s;
  __syncthreads();
  if (t < 64) {
    float tot = red[d] + red[64+d] + red[128+d] + red[192+d];
    atomicAdd(&qg[bh*64 + d], tot * (1.0f / (L_ * 8.0f)));   // /L /sqrt(64)
  }
}

// ---------------------------------------------------------------------------
// Kernel 3: logits[b,h,l] = qg[b,h,:]·k[b,l,h,:];  alpha = softmax_l * L
// grid = B*H blocks, 256 threads, 16 l's per thread (logits in registers).
// ---------------------------------------------------------------------------
__global__ __launch_bounds__(256) void alpha_kernel(
    const float* __restrict__ k, const float* __restrict__ qg,
    float* __restrict__ alpha)
{
  int bh = blockIdx.x; int b = bh >> 4, h = bh & 15;
  int t = threadIdx.x;
  __shared__ float qs[64];
  __shared__ float red[256];
  if (t < 64) qs[t] = qg[bh*64 + t];
  __syncthreads();

  float logit[16];
  float lmax = -1e30f;
  #pragma unroll
  for (int i = 0; i < 16; ++i) {
    int l = i*256 + t;
    const float4* kp = (const float4*)(k + (size_t)(b*L_ + l)*E_ + h*64);
    float dot = 0.f;
    #pragma unroll
    for (int j = 0; j < 16; ++j) {
      float4 kv = kp[j];
      dot += kv.x*qs[4*j] + kv.y*qs[4*j+1] + kv.z*qs[4*j+2] + kv.w*qs[4*j+3];
    }
    logit[i] = dot;
    lmax = fmaxf(lmax, dot);
  }
  red[t] = lmax; __syncthreads();
  for (int s = 128; s > 0; s >>= 1) {
    if (t < s) red[t] = fmaxf(red[t], red[t+s]);
    __syncthreads();
  }
  float bmax = red[0]; __syncthreads();
  float lsum = 0.f;
  #pragma unroll
  for (int i = 0; i < 16; ++i) { logit[i] = __expf(logit[i] - bmax); lsum += logit[i]; }
  red[t] = lsum; __syncthreads();
  for (int s = 128; s > 0; s >>= 1) {
    if (t < s) red[t] += red[t+s];
    __syncthreads();
  }
  float scale = (float)L_ / red[0];
  #pragma unroll
  for (int i = 0; i < 16; ++i)
    alpha[(size_t)bh * L_ + i*256 + t] = logit[i] * scale;
}

// ---------------------------------------------------------------------------
// Kernel 4: KV-state accumulation.
// S[b,h,d,v]  = sum_l g( k*alpha)[l,d] * v[l,v]      (+ sums over l of gk)
// Sm[b,h,d,v] = sum_l g(-k*alpha)[l,d] * v[l,v]      (+ sums of gmk)
// grid = (B*H, 8 chunks of 512 l's); fp32 atomics into zeroed S/Sm/sums.
// Thread t: d = t&63, v-block = (t>>6)*16  -> 16 (+16) accumulators.
// ---------------------------------------------------------------------------
__global__ __launch_bounds__(256) void state_kernel(
    const float* __restrict__ k, const float* __restrict__ v,
    const float* __restrict__ alpha,
    float* __restrict__ S, float* __restrict__ Sm,
    float* __restrict__ ksum, float* __restrict__ kmsum)
{
  int bh = blockIdx.x; int b = bh >> 4, h = bh & 15;
  int l0 = blockIdx.y * 512;
  __shared__ float gk[16][64], gmk[16][64], vt[16][64];
  int t = threadIdx.x;
  int d = t & 63, vb = (t >> 6) * 16;
  int lr = t >> 4, cc = (t & 15) * 4;
  float acc[16] = {}, accm[16] = {};
  float sgk = 0.f, sgmk = 0.f;

  for (int lt = 0; lt < 512; lt += 16) {
    int l = l0 + lt + lr;
    size_t off = (size_t)(b*L_ + l) * E_ + h*64 + cc;
    float4 k4 = *(const float4*)(k + off);
    float4 v4 = *(const float4*)(v + off);
    float av = alpha[(size_t)bh * L_ + l];
    __syncthreads();   // previous iteration's compute done before overwrite
    gk [lr][cc+0] = gfun( k4.x * av);  gmk[lr][cc+0] = gfun(-k4.x * av);
    gk [lr][cc+1] = gfun( k4.y * av);  gmk[lr][cc+1] = gfun(-k4.y * av);
    gk [lr][cc+2] = gfun( k4.z * av);  gmk[lr][cc+2] = gfun(-k4.z * av);
    gk [lr][cc+3] = gfun( k4.w * av);  gmk[lr][cc+3] = gfun(-k4.w * av);
    *(float4*)&vt[lr][cc] = v4;
    __syncthreads();
    #pragma unroll
    for (int l2 = 0; l2 < 16; ++l2) {
      float gkv = gk[l2][d], gmkv = gmk[l2][d];
      if (vb == 0) { sgk += gkv; sgmk += gmkv; }   // wave-uniform branch (wave 0)
      #pragma unroll
      for (int jj = 0; jj < 4; ++jj) {
        float4 vv = *(float4*)&vt[l2][vb + jj*4];
        acc [jj*4+0] += gkv *vv.x; acc [jj*4+1] += gkv *vv.y;
        acc [jj*4+2] += gkv *vv.z; acc [jj*4+3] += gkv *vv.w;
        accm[jj*4+0] += gmkv*vv.x; accm[jj*4+1] += gmkv*vv.y;
        accm[jj*4+2] += gmkv*vv.z; accm[jj*4+3] += gmkv*vv.w;
      }
    }
  }

  float* Sp  = S  + ((size_t)bh*64 + d)*64 + vb;
  float* Smp = Sm + ((size_t)bh*64 + d)*64 + vb;
  #pragma unroll
  for (int j = 0; j < 16; ++j) {
    atomicAdd(&Sp[j],  acc[j]);
    atomicAdd(&Smp[j], accm[j]);
  }
  if (t < 64) {
    atomicAdd(&ksum [bh*64 + d], sgk);
    atomicAdd(&kmsum[bh*64 + d], sgmk);
  }
}

// ---------------------------------------------------------------------------
// Kernel 5: output.
// out[b,l,h,v] = (gq·S[:,v] + gmq·Sm[:,v]) / (gq·ksum + gmq·kmsum + 1e-6)
// grid = (B*H, 8 chunks of 512 l's). States resident in LDS (32 KB).
// Each iteration: 4 l's x 64 v-threads; den via 64-lane butterfly per wave.
// ---------------------------------------------------------------------------
__global__ __launch_bounds__(256) void out_kernel(
    const float* __restrict__ q,
    const float* __restrict__ S, const float* __restrict__ Sm,
    const float* __restrict__ ksum, const float* __restrict__ kmsum,
    float* __restrict__ out)
{
  int bh = blockIdx.x; int b = bh >> 4, h = bh & 15;
  int l0 = blockIdx.y * 512;
  __shared__ float Ss[64][64], Sms[64][64];
  __shared__ float gq[4][64], gmq[4][64];
  __shared__ float ks[64], kms[64];
  __shared__ float dens[4];
  int t = threadIdx.x;
  #pragma unroll
  for (int i = 0; i < 4; ++i) {
    int idx = t*4 + i*1024;
    *(float4*)&((float*)Ss)[idx]  = *(const float4*)&S [(size_t)bh*4096 + idx];
    *(float4*)&((float*)Sms)[idx] = *(const float4*)&Sm[(size_t)bh*4096 + idx];
  }
  if (t < 64) { ks[t] = ksum[bh*64 + t]; kms[t] = kmsum[bh*64 + t]; }
  __syncthreads();

  int li = t >> 6, dv = t & 63;   // wave w handles l-slot w, lane = dv
  for (int l4 = 0; l4 < 512; l4 += 4) {
    int l = l0 + l4 + li;
    float qv = q[(size_t)(b*L_ + l) * E_ + h*64 + dv];
    float g1 = gfun(qv), g2 = gfun(-qv);
    gq[li][dv] = g1; gmq[li][dv] = g2;
    float c = g1*ks[dv] + g2*kms[dv];
    #pragma unroll
    for (int off = 32; off > 0; off >>= 1) c += __shfl_down(c, off);
    if (dv == 0) dens[li] = c;
    __syncthreads();
    float num = 0.f;
    #pragma unroll
    for (int dd = 0; dd < 64; ++dd)
      num += gq[li][dd]*Ss[dd][dv] + gmq[li][dd]*Sms[dd][dv];
    out[(size_t)(b*L_ + l) * E_ + h*64 + dv] = num / (dens[li] + 1e-6f);
    __syncthreads();
  }
}

// ---------------------------------------------------------------------------
// Workspace layout (floats):
//   q     : [0, 16777216)
//   k     : [16777216, 33554432)
//   qg    : [33554432, +4096)        \
//   S     : [33558528, +262144)       |  zeroed via one hipMemsetAsync
//   Sm    : [33820672, +262144)       |  (contiguous region)
//   ksum  : [34082816, +4096)         |
//   kmsum : [34086912, +4096)        /
//   alpha : [34091008, +262144)  -> end 34353152 floats = 137.4 MB
//   v lives in d_out (fully overwritten by out_kernel afterwards).
// ---------------------------------------------------------------------------
extern "C" void kernel_launch(void* const* d_in, const int* in_sizes, int n_in,
                              void* d_out, int out_size, void* d_ws, size_t ws_size,
                              hipStream_t stream) {
  const float* x  = (const float*)d_in[0];
  const float* Wq = (const float*)d_in[1];
  const float* bq = (const float*)d_in[2];
  const float* Wk = (const float*)d_in[3];
  const float* bk = (const float*)d_in[4];
  const float* Wv = (const float*)d_in[5];
  const float* bv = (const float*)d_in[6];
  float* out = (float*)d_out;
  float* ws  = (float*)d_ws;

  float* q     = ws;
  float* k     = ws + 16777216;
  float* qg    = ws + 33554432;
  float* S     = ws + 33558528;
  float* Sm    = ws + 33820672;
  float* ksum  = ws + 34082816;
  float* kmsum = ws + 34086912;
  float* alpha = ws + 34091008;
  float* v     = out;   // stage-A v output; consumed by state_kernel, then overwritten

  // zero qg + S + Sm + ksum + kmsum (contiguous: 536576 floats)
  hipMemsetAsync(qg, 0, 536576 * sizeof(float), stream);

  qkv_gemm<<<dim3(E_/BN, M_/BM, 3), 256, 0, stream>>>(
      x, Wq, bq, Wk, bk, Wv, bv, q, k, v);
  qglobal_kernel<<<dim3(B_*H_, 4), 256, 0, stream>>>(q, qg);
  alpha_kernel<<<B_*H_, 256, 0, stream>>>(k, qg, alpha);
  state_kernel<<<dim3(B_*H_, 8), 256, 0, stream>>>(k, v, alpha, S, Sm, ksum, kmsum);
  out_kernel<<<dim3(B_*H_, 8), 256, 0, stream>>>(q, S, Sm, ksum, kmsum, out);
}

// Round 2
// 1284.765 us; speedup vs baseline: 1.5445x; 1.5445x over previous
//
#include <hip/hip_runtime.h>
#include <hip/hip_bf16.h>
#include <math.h>

// Problem constants
#define B_ 4
#define L_ 4096
#define E_ 1024
#define H_ 16
#define D_ 64
#define M_ (B_*L_)   // 16384 rows

typedef __attribute__((ext_vector_type(8))) short s8;     // 8 bf16 (4 VGPRs)
typedef __attribute__((ext_vector_type(4))) float f4;     // MFMA C/D

// g(x) = (softplus(5x)/5)^2, numerically stable
__device__ __forceinline__ float gfun(float x) {
  float z = 5.0f * x;
  float sp = fmaxf(z, 0.0f) + log1pf(__expf(-fabsf(z)));
  sp *= 0.2f;
  return sp * sp;
}

__device__ __forceinline__ unsigned short f2bf(float v) {
  __hip_bfloat16 h = __float2bfloat16(v);
  return *reinterpret_cast<unsigned short*>(&h);
}
__device__ __forceinline__ float bf2f(unsigned short u) {
  __hip_bfloat16 h = *reinterpret_cast<__hip_bfloat16*>(&u);
  return __bfloat162float(h);
}

// async global->LDS, 16 B per lane
__device__ __forceinline__ void gload16(const void* g, void* l) {
  __builtin_amdgcn_global_load_lds(
      (const __attribute__((address_space(1))) void*)g,
      (__attribute__((address_space(3))) void*)l, 16, 0, 0);
}

// ---------------------------------------------------------------------------
// Prep 1: split x (fp32 [16384,1024]) into bf16 hi|lo  -> Ah [16384, 2048]
//   Ah[m][e]      = bf16(x[m][e])          (hi)
//   Ah[m][1024+e] = bf16(x - float(hi))    (lo)
// ---------------------------------------------------------------------------
__global__ __launch_bounds__(256) void split_x(
    const float* __restrict__ x, unsigned short* __restrict__ Ah)
{
  int idx = blockIdx.x * 256 + threadIdx.x;        // float4 index
  int m = idx >> 8, e = (idx & 255) * 4;
  float4 x4 = ((const float4*)x)[idx];
  float vv[4] = {x4.x, x4.y, x4.z, x4.w};
  ushort4 hi, lo;
  unsigned short h;
  h = f2bf(vv[0]); hi.x = h; lo.x = f2bf(vv[0] - bf2f(h));
  h = f2bf(vv[1]); hi.y = h; lo.y = f2bf(vv[1] - bf2f(h));
  h = f2bf(vv[2]); hi.z = h; lo.z = f2bf(vv[2] - bf2f(h));
  h = f2bf(vv[3]); hi.w = h; lo.w = f2bf(vv[3] - bf2f(h));
  *(ushort4*)&Ah[(size_t)m * 2048 + e]        = hi;
  *(ushort4*)&Ah[(size_t)m * 2048 + 1024 + e] = lo;
}

// ---------------------------------------------------------------------------
// Prep 2: transpose + split each W (fp32 [1024,1024], row=k, col=n)
//   -> Bt[z] [1024, 2048] bf16 with Bt[n][k]=hi, Bt[n][1024+k]=lo
// ---------------------------------------------------------------------------
__global__ __launch_bounds__(256) void split_wT(
    const float* __restrict__ Wq, const float* __restrict__ Wk,
    const float* __restrict__ Wv, unsigned short* __restrict__ Bt)
{
  int z = blockIdx.z;
  const float* W = (z == 0) ? Wq : (z == 1) ? Wk : Wv;
  __shared__ float tile[32][33];
  int t = threadIdx.x;
  int tx = t & 31, ty = t >> 5;                    // ty 0..7
  int k0 = blockIdx.x * 32, n0 = blockIdx.y * 32;
  #pragma unroll
  for (int i = 0; i < 4; ++i)
    tile[ty + i*8][tx] = W[(size_t)(k0 + ty + i*8) * 1024 + n0 + tx];
  __syncthreads();
  unsigned short* Bz = Bt + (size_t)z * 2097152;
  #pragma unroll
  for (int i = 0; i < 4; ++i) {
    int n = n0 + ty + i*8, kk = k0 + tx;
    float v = tile[tx][ty + i*8];
    unsigned short h = f2bf(v);
    Bz[(size_t)n * 2048 + kk]        = h;
    Bz[(size_t)n * 2048 + 1024 + kk] = f2bf(v - bf2f(h));
  }
}

// ---------------------------------------------------------------------------
// Kernel 1: QKV projection via split-bf16 MFMA GEMM (Ootomo 3-product).
// C = Ahi*Bhi + Ahi*Blo + Alo*Bhi over a logical K'=3072 loop with
// segment-mapped offsets into Ah [M,2048] and Bt [N,2048] (both k-inner).
// m97 structure: 128x128 tile, BK=32, global_load_lds(16B), 16x16x32 MFMA,
// 2x2 waves x 4x4 frags. grid = (N/128=8, M/128=128, 3).
// ---------------------------------------------------------------------------
__global__ __launch_bounds__(256) void qkv_mfma(
    const unsigned short* __restrict__ Ah, const unsigned short* __restrict__ Bt,
    const float* __restrict__ bq, const float* __restrict__ bk,
    const float* __restrict__ bv,
    float* __restrict__ qo, float* __restrict__ ko, float* __restrict__ vo)
{
  const int z = blockIdx.z;
  const float* bias = (z == 0) ? bq : (z == 1) ? bk : bv;
  float* out = (z == 0) ? qo : (z == 1) ? ko : vo;

  __shared__ unsigned short As[4096];   // [128][32]
  __shared__ unsigned short Bs[4096];   // [128][32]

  const int t = threadIdx.x;
  const int bm = blockIdx.y * 128;
  const int bn = blockIdx.x * 128;

  // staging: thread t covers tile-row t>>2 (plus +64 on issue 2), 8 bf16 at (t&3)*8
  const unsigned short* Ag0 = Ah + (size_t)(bm + (t >> 2)) * 2048 + (t & 3) * 8;
  const unsigned short* Bg0 = Bt + (size_t)z * 2097152
                              + (size_t)(bn + (t >> 2)) * 2048 + (t & 3) * 8;
  unsigned short* Asd0 = &As[t * 8];
  unsigned short* Asd1 = &As[2048 + t * 8];
  unsigned short* Bsd0 = &Bs[t * 8];
  unsigned short* Bsd1 = &Bs[2048 + t * 8];

  const int lane = t & 63;
  const int wm = (t >> 6) & 1, wn = t >> 7;
  const int fr = lane & 15;          // frag row (m for A, n for B), also C col
  const int fq = lane >> 4;          // quad: k-group for A/B, row-group for C

  f4 acc[4][4] = {};

  for (int k0 = 0; k0 < 3072; k0 += 32) {
    int seg = k0 >> 10, kk = k0 & 1023;
    int kA = kk + ((seg == 2) ? 1024 : 0);   // A: [hi, hi, lo]
    int kB = kk + ((seg == 1) ? 1024 : 0);   // B: [hi, lo, hi]
    gload16(Ag0 + kA, Asd0);
    gload16(Ag0 + 131072 + kA, Asd1);        // +64 rows
    gload16(Bg0 + kB, Bsd0);
    gload16(Bg0 + 131072 + kB, Bsd1);
    __syncthreads();                          // drains vmcnt: tiles resident

    s8 a[4], b[4];
    #pragma unroll
    for (int i = 0; i < 4; ++i)
      a[i] = *(const s8*)&As[(wm * 64 + i * 16 + fr) * 32 + fq * 8];
    #pragma unroll
    for (int j = 0; j < 4; ++j)
      b[j] = *(const s8*)&Bs[(wn * 64 + j * 16 + fr) * 32 + fq * 8];
    #pragma unroll
    for (int i = 0; i < 4; ++i)
      #pragma unroll
      for (int j = 0; j < 4; ++j)
        acc[i][j] = __builtin_amdgcn_mfma_f32_16x16x32_bf16(a[i], b[j], acc[i][j], 0, 0, 0);
    __syncthreads();                          // compute done before next overwrite
  }

  // epilogue: C/D layout col=lane&15, row=(lane>>4)*4+reg
  float bv4[4];
  #pragma unroll
  for (int j = 0; j < 4; ++j) bv4[j] = bias[bn + wn * 64 + j * 16 + fr];
  #pragma unroll
  for (int i = 0; i < 4; ++i) {
    int mrow = bm + wm * 64 + i * 16 + fq * 4;
    #pragma unroll
    for (int j = 0; j < 4; ++j) {
      int ncol = bn + wn * 64 + j * 16 + fr;
      #pragma unroll
      for (int r = 0; r < 4; ++r)
        out[(size_t)(mrow + r) * E_ + ncol] = acc[i][j][r] + bv4[j];
    }
  }
}

// ---------------------------------------------------------------------------
// Kernel 2: q_global[b,h,d] = mean_l q[b,l,h,d] / sqrt(D)
// ---------------------------------------------------------------------------
__global__ __launch_bounds__(256) void qglobal_kernel(
    const float* __restrict__ q, float* __restrict__ qg)
{
  int bh = blockIdx.x;
  int b = bh >> 4, h = bh & 15;
  int t = threadIdx.x;
  int d = t & 63, c = t >> 6;
  int l0 = blockIdx.y * 1024 + c * 256;
  const float* base = q + (size_t)(b * L_ + l0) * E_ + h * 64 + d;
  float s = 0.f;
  #pragma unroll 8
  for (int i = 0; i < 256; ++i) s += base[(size_t)i * E_];
  __shared__ float red[256];
  red[t] = s;
  __syncthreads();
  if (t < 64) {
    float tot = red[d] + red[64+d] + red[128+d] + red[192+d];
    atomicAdd(&qg[bh*64 + d], tot * (1.0f / (L_ * 8.0f)));   // /L /sqrt(64)
  }
}

// ---------------------------------------------------------------------------
// Kernel 3: alpha = softmax_l(qg . k) * L
// ---------------------------------------------------------------------------
__global__ __launch_bounds__(256) void alpha_kernel(
    const float* __restrict__ k, const float* __restrict__ qg,
    float* __restrict__ alpha)
{
  int bh = blockIdx.x; int b = bh >> 4, h = bh & 15;
  int t = threadIdx.x;
  __shared__ float qs[64];
  __shared__ float red[256];
  if (t < 64) qs[t] = qg[bh*64 + t];
  __syncthreads();

  float logit[16];
  float lmax = -1e30f;
  #pragma unroll
  for (int i = 0; i < 16; ++i) {
    int l = i*256 + t;
    const float4* kp = (const float4*)(k + (size_t)(b*L_ + l)*E_ + h*64);
    float dot = 0.f;
    #pragma unroll
    for (int j = 0; j < 16; ++j) {
      float4 kv = kp[j];
      dot += kv.x*qs[4*j] + kv.y*qs[4*j+1] + kv.z*qs[4*j+2] + kv.w*qs[4*j+3];
    }
    logit[i] = dot;
    lmax = fmaxf(lmax, dot);
  }
  red[t] = lmax; __syncthreads();
  for (int s = 128; s > 0; s >>= 1) {
    if (t < s) red[t] = fmaxf(red[t], red[t+s]);
    __syncthreads();
  }
  float bmax = red[0]; __syncthreads();
  float lsum = 0.f;
  #pragma unroll
  for (int i = 0; i < 16; ++i) { logit[i] = __expf(logit[i] - bmax); lsum += logit[i]; }
  red[t] = lsum; __syncthreads();
  for (int s = 128; s > 0; s >>= 1) {
    if (t < s) red[t] += red[t+s];
    __syncthreads();
  }
  float scale = (float)L_ / red[0];
  #pragma unroll
  for (int i = 0; i < 16; ++i)
    alpha[(size_t)bh * L_ + i*256 + t] = logit[i] * scale;
}

// ---------------------------------------------------------------------------
// Kernel 4: KV-state accumulation (unchanged from R1)
// ---------------------------------------------------------------------------
__global__ __launch_bounds__(256) void state_kernel(
    const float* __restrict__ k, const float* __restrict__ v,
    const float* __restrict__ alpha,
    float* __restrict__ S, float* __restrict__ Sm,
    float* __restrict__ ksum, float* __restrict__ kmsum)
{
  int bh = blockIdx.x; int b = bh >> 4, h = bh & 15;
  int l0 = blockIdx.y * 512;
  __shared__ float gk[16][64], gmk[16][64], vt[16][64];
  int t = threadIdx.x;
  int d = t & 63, vb = (t >> 6) * 16;
  int lr = t >> 4, cc = (t & 15) * 4;
  float acc[16] = {}, accm[16] = {};
  float sgk = 0.f, sgmk = 0.f;

  for (int lt = 0; lt < 512; lt += 16) {
    int l = l0 + lt + lr;
    size_t off = (size_t)(b*L_ + l) * E_ + h*64 + cc;
    float4 k4 = *(const float4*)(k + off);
    float4 v4 = *(const float4*)(v + off);
    float av = alpha[(size_t)bh * L_ + l];
    __syncthreads();
    gk [lr][cc+0] = gfun( k4.x * av);  gmk[lr][cc+0] = gfun(-k4.x * av);
    gk [lr][cc+1] = gfun( k4.y * av);  gmk[lr][cc+1] = gfun(-k4.y * av);
    gk [lr][cc+2] = gfun( k4.z * av);  gmk[lr][cc+2] = gfun(-k4.z * av);
    gk [lr][cc+3] = gfun( k4.w * av);  gmk[lr][cc+3] = gfun(-k4.w * av);
    *(float4*)&vt[lr][cc] = v4;
    __syncthreads();
    #pragma unroll
    for (int l2 = 0; l2 < 16; ++l2) {
      float gkv = gk[l2][d], gmkv = gmk[l2][d];
      if (vb == 0) { sgk += gkv; sgmk += gmkv; }
      #pragma unroll
      for (int jj = 0; jj < 4; ++jj) {
        float4 vv = *(float4*)&vt[l2][vb + jj*4];
        acc [jj*4+0] += gkv *vv.x; acc [jj*4+1] += gkv *vv.y;
        acc [jj*4+2] += gkv *vv.z; acc [jj*4+3] += gkv *vv.w;
        accm[jj*4+0] += gmkv*vv.x; accm[jj*4+1] += gmkv*vv.y;
        accm[jj*4+2] += gmkv*vv.z; accm[jj*4+3] += gmkv*vv.w;
      }
    }
  }

  float* Sp  = S  + ((size_t)bh*64 + d)*64 + vb;
  float* Smp = Sm + ((size_t)bh*64 + d)*64 + vb;
  #pragma unroll
  for (int j = 0; j < 16; ++j) {
    atomicAdd(&Sp[j],  acc[j]);
    atomicAdd(&Smp[j], accm[j]);
  }
  if (t < 64) {
    atomicAdd(&ksum [bh*64 + d], sgk);
    atomicAdd(&kmsum[bh*64 + d], sgmk);
  }
}

// ---------------------------------------------------------------------------
// Kernel 5: output (unchanged from R1)
// ---------------------------------------------------------------------------
__global__ __launch_bounds__(256) void out_kernel(
    const float* __restrict__ q,
    const float* __restrict__ S, const float* __restrict__ Sm,
    const float* __restrict__ ksum, const float* __restrict__ kmsum,
    float* __restrict__ out)
{
  int bh = blockIdx.x; int b = bh >> 4, h = bh & 15;
  int l0 = blockIdx.y * 512;
  __shared__ float Ss[64][64], Sms[64][64];
  __shared__ float gq[4][64], gmq[4][64];
  __shared__ float ks[64], kms[64];
  __shared__ float dens[4];
  int t = threadIdx.x;
  #pragma unroll
  for (int i = 0; i < 4; ++i) {
    int idx = t*4 + i*1024;
    *(float4*)&((float*)Ss)[idx]  = *(const float4*)&S [(size_t)bh*4096 + idx];
    *(float4*)&((float*)Sms)[idx] = *(const float4*)&Sm[(size_t)bh*4096 + idx];
  }
  if (t < 64) { ks[t] = ksum[bh*64 + t]; kms[t] = kmsum[bh*64 + t]; }
  __syncthreads();

  int li = t >> 6, dv = t & 63;
  for (int l4 = 0; l4 < 512; l4 += 4) {
    int l = l0 + l4 + li;
    float qv = q[(size_t)(b*L_ + l) * E_ + h*64 + dv];
    float g1 = gfun(qv), g2 = gfun(-qv);
    gq[li][dv] = g1; gmq[li][dv] = g2;
    float c = g1*ks[dv] + g2*kms[dv];
    #pragma unroll
    for (int off = 32; off > 0; off >>= 1) c += __shfl_down(c, off);
    if (dv == 0) dens[li] = c;
    __syncthreads();
    float num = 0.f;
    #pragma unroll
    for (int dd = 0; dd < 64; ++dd)
      num += gq[li][dd]*Ss[dd][dv] + gmq[li][dd]*Sms[dd][dv];
    out[(size_t)(b*L_ + l) * E_ + h*64 + dv] = num / (dens[li] + 1e-6f);
    __syncthreads();
  }
}

// ---------------------------------------------------------------------------
// Workspace layout (float units):
//   q     : 0          .. 16,777,216
//   k     : 16,777,216 .. 33,554,432
//   qg    : 33,554,432 (+4096)     \
//   S     : 33,558,528 (+262,144)   |  zeroed via one hipMemsetAsync
//   Sm    : 33,820,672 (+262,144)   |  (contiguous 536,576 floats)
//   ksum  : 34,082,816 (+4096)      |
//   kmsum : 34,086,912 (+4096)     /
//   alpha : 34,091,008 (+262,144)
//   Ah    : f-off 34,353,152, 33,554,432 bf16 (x split [16384,2048])
//   Bt    : f-off 51,130,368,  6,291,456 bf16 (3 x WT split [1024,2048])
//   end   : 54,276,096 floats = 217.1 MB
//   v lives in d_out (consumed by state_kernel, overwritten by out_kernel).
// ---------------------------------------------------------------------------
extern "C" void kernel_launch(void* const* d_in, const int* in_sizes, int n_in,
                              void* d_out, int out_size, void* d_ws, size_t ws_size,
                              hipStream_t stream) {
  const float* x  = (const float*)d_in[0];
  const float* Wq = (const float*)d_in[1];
  const float* bq = (const float*)d_in[2];
  const float* Wk = (const float*)d_in[3];
  const float* bk = (const float*)d_in[4];
  const float* Wv = (const float*)d_in[5];
  const float* bv = (const float*)d_in[6];
  float* out = (float*)d_out;
  float* ws  = (float*)d_ws;

  float* q     = ws;
  float* k     = ws + 16777216;
  float* qg    = ws + 33554432;
  float* S     = ws + 33558528;
  float* Sm    = ws + 33820672;
  float* ksum  = ws + 34082816;
  float* kmsum = ws + 34086912;
  float* alpha = ws + 34091008;
  unsigned short* Ah = (unsigned short*)(ws + 34353152);
  unsigned short* Bt = (unsigned short*)(ws + 51130368);
  float* v     = out;

  hipMemsetAsync(qg, 0, 536576 * sizeof(float), stream);

  split_x<<<16384, 256, 0, stream>>>(x, Ah);
  split_wT<<<dim3(32, 32, 3), 256, 0, stream>>>(Wq, Wk, Wv, Bt);
  qkv_mfma<<<dim3(8, 128, 3), 256, 0, stream>>>(Ah, Bt, bq, bk, bv, q, k, v);
  qglobal_kernel<<<dim3(B_*H_, 4), 256, 0, stream>>>(q, qg);
  alpha_kernel<<<B_*H_, 256, 0, stream>>>(k, qg, alpha);
  state_kernel<<<dim3(B_*H_, 8), 256, 0, stream>>>(k, v, alpha, S, Sm, ksum, kmsum);
  out_kernel<<<dim3(B_*H_, 8), 256, 0, stream>>>(q, S, Sm, ksum, kmsum, out);
}

// Round 3
// 1053.397 us; speedup vs baseline: 1.8837x; 1.2196x over previous
//
#include <hip/hip_runtime.h>
#include <hip/hip_bf16.h>
#include <math.h>

// Problem constants
#define B_ 4
#define L_ 4096
#define E_ 1024
#define H_ 16
#define D_ 64
#define M_ (B_*L_)   // 16384 rows

typedef __attribute__((ext_vector_type(8))) short s8;     // 8 bf16 (4 VGPRs)
typedef __attribute__((ext_vector_type(4))) float f4;     // MFMA C/D

// g(x) = (softplus(5x)/5)^2, numerically stable
__device__ __forceinline__ float gfun(float x) {
  float z = 5.0f * x;
  float sp = fmaxf(z, 0.0f) + log1pf(__expf(-fabsf(z)));
  sp *= 0.2f;
  return sp * sp;
}

__device__ __forceinline__ unsigned short f2bf(float v) {
  __hip_bfloat16 h = __float2bfloat16(v);
  return *reinterpret_cast<unsigned short*>(&h);
}
__device__ __forceinline__ float bf2f(unsigned short u) {
  __hip_bfloat16 h = *reinterpret_cast<__hip_bfloat16*>(&u);
  return __bfloat162float(h);
}

// async global->LDS, 16 B per lane
__device__ __forceinline__ void gload16(const void* g, void* l) {
  __builtin_amdgcn_global_load_lds(
      (const __attribute__((address_space(1))) void*)g,
      (__attribute__((address_space(3))) void*)l, 16, 0, 0);
}

// ---------------------------------------------------------------------------
// Prep 1: split x (fp32 [16384,1024]) into bf16 hi|lo  -> Ah [16384, 2048]
// ---------------------------------------------------------------------------
__global__ __launch_bounds__(256) void split_x(
    const float* __restrict__ x, unsigned short* __restrict__ Ah)
{
  int idx = blockIdx.x * 256 + threadIdx.x;        // float4 index
  int m = idx >> 8, e = (idx & 255) * 4;
  float4 x4 = ((const float4*)x)[idx];
  float vv[4] = {x4.x, x4.y, x4.z, x4.w};
  ushort4 hi, lo;
  unsigned short h;
  h = f2bf(vv[0]); hi.x = h; lo.x = f2bf(vv[0] - bf2f(h));
  h = f2bf(vv[1]); hi.y = h; lo.y = f2bf(vv[1] - bf2f(h));
  h = f2bf(vv[2]); hi.z = h; lo.z = f2bf(vv[2] - bf2f(h));
  h = f2bf(vv[3]); hi.w = h; lo.w = f2bf(vv[3] - bf2f(h));
  *(ushort4*)&Ah[(size_t)m * 2048 + e]        = hi;
  *(ushort4*)&Ah[(size_t)m * 2048 + 1024 + e] = lo;
}

// ---------------------------------------------------------------------------
// Prep 2: transpose + split each W -> Bt[z] [1024, 2048] bf16 (hi | lo)
// ---------------------------------------------------------------------------
__global__ __launch_bounds__(256) void split_wT(
    const float* __restrict__ Wq, const float* __restrict__ Wk,
    const float* __restrict__ Wv, unsigned short* __restrict__ Bt)
{
  int z = blockIdx.z;
  const float* W = (z == 0) ? Wq : (z == 1) ? Wk : Wv;
  __shared__ float tile[32][33];
  int t = threadIdx.x;
  int tx = t & 31, ty = t >> 5;                    // ty 0..7
  int k0 = blockIdx.x * 32, n0 = blockIdx.y * 32;
  #pragma unroll
  for (int i = 0; i < 4; ++i)
    tile[ty + i*8][tx] = W[(size_t)(k0 + ty + i*8) * 1024 + n0 + tx];
  __syncthreads();
  unsigned short* Bz = Bt + (size_t)z * 2097152;
  #pragma unroll
  for (int i = 0; i < 4; ++i) {
    int n = n0 + ty + i*8, kk = k0 + tx;
    float v = tile[tx][ty + i*8];
    unsigned short h = f2bf(v);
    Bz[(size_t)n * 2048 + kk]        = h;
    Bz[(size_t)n * 2048 + 1024 + kk] = f2bf(v - bf2f(h));
  }
}

// ---------------------------------------------------------------------------
// Kernel 1: QKV projection via split-bf16 MFMA GEMM (3-product, K'=3072).
// (unchanged from R2: 746 TF, MfmaUtil 33%)
// ---------------------------------------------------------------------------
__global__ __launch_bounds__(256) void qkv_mfma(
    const unsigned short* __restrict__ Ah, const unsigned short* __restrict__ Bt,
    const float* __restrict__ bq, const float* __restrict__ bk,
    const float* __restrict__ bv,
    float* __restrict__ qo, float* __restrict__ ko, float* __restrict__ vo)
{
  const int z = blockIdx.z;
  const float* bias = (z == 0) ? bq : (z == 1) ? bk : bv;
  float* out = (z == 0) ? qo : (z == 1) ? ko : vo;

  __shared__ unsigned short As[4096];   // [128][32]
  __shared__ unsigned short Bs[4096];   // [128][32]

  const int t = threadIdx.x;
  const int bm = blockIdx.y * 128;
  const int bn = blockIdx.x * 128;

  const unsigned short* Ag0 = Ah + (size_t)(bm + (t >> 2)) * 2048 + (t & 3) * 8;
  const unsigned short* Bg0 = Bt + (size_t)z * 2097152
                              + (size_t)(bn + (t >> 2)) * 2048 + (t & 3) * 8;
  unsigned short* Asd0 = &As[t * 8];
  unsigned short* Asd1 = &As[2048 + t * 8];
  unsigned short* Bsd0 = &Bs[t * 8];
  unsigned short* Bsd1 = &Bs[2048 + t * 8];

  const int lane = t & 63;
  const int wm = (t >> 6) & 1, wn = t >> 7;
  const int fr = lane & 15;
  const int fq = lane >> 4;

  f4 acc[4][4] = {};

  for (int k0 = 0; k0 < 3072; k0 += 32) {
    int seg = k0 >> 10, kk = k0 & 1023;
    int kA = kk + ((seg == 2) ? 1024 : 0);   // A: [hi, hi, lo]
    int kB = kk + ((seg == 1) ? 1024 : 0);   // B: [hi, lo, hi]
    gload16(Ag0 + kA, Asd0);
    gload16(Ag0 + 131072 + kA, Asd1);
    gload16(Bg0 + kB, Bsd0);
    gload16(Bg0 + 131072 + kB, Bsd1);
    __syncthreads();

    s8 a[4], b[4];
    #pragma unroll
    for (int i = 0; i < 4; ++i)
      a[i] = *(const s8*)&As[(wm * 64 + i * 16 + fr) * 32 + fq * 8];
    #pragma unroll
    for (int j = 0; j < 4; ++j)
      b[j] = *(const s8*)&Bs[(wn * 64 + j * 16 + fr) * 32 + fq * 8];
    #pragma unroll
    for (int i = 0; i < 4; ++i)
      #pragma unroll
      for (int j = 0; j < 4; ++j)
        acc[i][j] = __builtin_amdgcn_mfma_f32_16x16x32_bf16(a[i], b[j], acc[i][j], 0, 0, 0);
    __syncthreads();
  }

  float bv4[4];
  #pragma unroll
  for (int j = 0; j < 4; ++j) bv4[j] = bias[bn + wn * 64 + j * 16 + fr];
  #pragma unroll
  for (int i = 0; i < 4; ++i) {
    int mrow = bm + wm * 64 + i * 16 + fq * 4;
    #pragma unroll
    for (int j = 0; j < 4; ++j) {
      int ncol = bn + wn * 64 + j * 16 + fr;
      #pragma unroll
      for (int r = 0; r < 4; ++r)
        out[(size_t)(mrow + r) * E_ + ncol] = acc[i][j][r] + bv4[j];
    }
  }
}

// ---------------------------------------------------------------------------
// Kernel 2: q_global[b,h,d] = mean_l q[b,l,h,d] / sqrt(D)
// ---------------------------------------------------------------------------
__global__ __launch_bounds__(256) void qglobal_kernel(
    const float* __restrict__ q, float* __restrict__ qg)
{
  int bh = blockIdx.x;
  int b = bh >> 4, h = bh & 15;
  int t = threadIdx.x;
  int d = t & 63, c = t >> 6;
  int l0 = blockIdx.y * 1024 + c * 256;
  const float* base = q + (size_t)(b * L_ + l0) * E_ + h * 64 + d;
  float s = 0.f;
  #pragma unroll 8
  for (int i = 0; i < 256; ++i) s += base[(size_t)i * E_];
  __shared__ float red[256];
  red[t] = s;
  __syncthreads();
  if (t < 64) {
    float tot = red[d] + red[64+d] + red[128+d] + red[192+d];
    atomicAdd(&qg[bh*64 + d], tot * (1.0f / (L_ * 8.0f)));   // /L /sqrt(64)
  }
}

// ---------------------------------------------------------------------------
// Kernel 3: alpha phase 1.  aexp[bh,l] = exp(qg . k[l]); denom[bh] += sum.
// No max-subtraction: logits = (mean_l q / sqrt(D)) . k are O(0.05) by
// construction — exp cannot overflow; softmax is shift-invariant.
// grid = (64 bh, 8 chunks of 512 l).
// ---------------------------------------------------------------------------
__global__ __launch_bounds__(256) void alpha_p1(
    const float* __restrict__ k, const float* __restrict__ qg,
    float* __restrict__ aexp, float* __restrict__ denom)
{
  int bh = blockIdx.x; int b = bh >> 4, h = bh & 15;
  int l0 = blockIdx.y * 512;
  int t = threadIdx.x;
  __shared__ float qs[64];
  __shared__ float red[256];
  if (t < 64) qs[t] = qg[bh*64 + t];
  __syncthreads();

  float sum = 0.f;
  #pragma unroll
  for (int i = 0; i < 2; ++i) {
    int l = l0 + i*256 + t;
    const float4* kp = (const float4*)(k + (size_t)(b*L_ + l)*E_ + h*64);
    float dot = 0.f;
    #pragma unroll
    for (int j = 0; j < 16; ++j) {
      float4 kv = kp[j];
      dot += kv.x*qs[4*j] + kv.y*qs[4*j+1] + kv.z*qs[4*j+2] + kv.w*qs[4*j+3];
    }
    float e = __expf(dot);
    aexp[(size_t)bh * L_ + l] = e;
    sum += e;
  }
  red[t] = sum; __syncthreads();
  for (int s = 128; s > 0; s >>= 1) {
    if (t < s) red[t] += red[t+s];
    __syncthreads();
  }
  if (t == 0) atomicAdd(&denom[bh], red[0]);
}

// ---------------------------------------------------------------------------
// Kernel 4: KV-state accumulation.  alpha = aexp * (L/denom[bh]) on the fly.
// ---------------------------------------------------------------------------
__global__ __launch_bounds__(256) void state_kernel(
    const float* __restrict__ k, const float* __restrict__ v,
    const float* __restrict__ aexp, const float* __restrict__ denom,
    float* __restrict__ S, float* __restrict__ Sm,
    float* __restrict__ ksum, float* __restrict__ kmsum)
{
  int bh = blockIdx.x; int b = bh >> 4, h = bh & 15;
  int l0 = blockIdx.y * 512;
  float scale = (float)L_ / denom[bh];
  __shared__ float gk[16][64], gmk[16][64], vt[16][64];
  int t = threadIdx.x;
  int d = t & 63, vb = (t >> 6) * 16;
  int lr = t >> 4, cc = (t & 15) * 4;
  float acc[16] = {}, accm[16] = {};
  float sgk = 0.f, sgmk = 0.f;

  for (int lt = 0; lt < 512; lt += 16) {
    int l = l0 + lt + lr;
    size_t off = (size_t)(b*L_ + l) * E_ + h*64 + cc;
    float4 k4 = *(const float4*)(k + off);
    float4 v4 = *(const float4*)(v + off);
    float av = aexp[(size_t)bh * L_ + l] * scale;
    __syncthreads();
    gk [lr][cc+0] = gfun( k4.x * av);  gmk[lr][cc+0] = gfun(-k4.x * av);
    gk [lr][cc+1] = gfun( k4.y * av);  gmk[lr][cc+1] = gfun(-k4.y * av);
    gk [lr][cc+2] = gfun( k4.z * av);  gmk[lr][cc+2] = gfun(-k4.z * av);
    gk [lr][cc+3] = gfun( k4.w * av);  gmk[lr][cc+3] = gfun(-k4.w * av);
    *(float4*)&vt[lr][cc] = v4;
    __syncthreads();
    #pragma unroll
    for (int l2 = 0; l2 < 16; ++l2) {
      float gkv = gk[l2][d], gmkv = gmk[l2][d];
      if (vb == 0) { sgk += gkv; sgmk += gmkv; }
      #pragma unroll
      for (int jj = 0; jj < 4; ++jj) {
        float4 vv = *(float4*)&vt[l2][vb + jj*4];
        acc [jj*4+0] += gkv *vv.x; acc [jj*4+1] += gkv *vv.y;
        acc [jj*4+2] += gkv *vv.z; acc [jj*4+3] += gkv *vv.w;
        accm[jj*4+0] += gmkv*vv.x; accm[jj*4+1] += gmkv*vv.y;
        accm[jj*4+2] += gmkv*vv.z; accm[jj*4+3] += gmkv*vv.w;
      }
    }
  }

  float* Sp  = S  + ((size_t)bh*64 + d)*64 + vb;
  float* Smp = Sm + ((size_t)bh*64 + d)*64 + vb;
  #pragma unroll
  for (int j = 0; j < 16; ++j) {
    atomicAdd(&Sp[j],  acc[j]);
    atomicAdd(&Smp[j], accm[j]);
  }
  if (t < 64) {
    atomicAdd(&ksum [bh*64 + d], sgk);
    atomicAdd(&kmsum[bh*64 + d], sgmk);
  }
}

// ---------------------------------------------------------------------------
// Kernel 5: output, register-tiled fp32 GEMM microkernel.
// Per block: (bh, chunk of 64 l's).  out[l,v] = (gq[l,:]·S[:,v] +
// gmq[l,:]·Sm[:,v]) / (gq·ksum + gmq·kmsum + 1e-6).
// LDS: Gq/Gm [dd][l] (16 KB each) + Ss/Sms (16 KB each) = 64 KB exactly.
// 256 threads as 16x16; 4 l x 4 v micro-tile; den fused (ksum from global,
// wave-uniform L1-resident loads).  Per kk: 4 ds_read_b128 + 40 FMA.
// ---------------------------------------------------------------------------
__global__ __launch_bounds__(256) void out_kernel(
    const float* __restrict__ q,
    const float* __restrict__ S, const float* __restrict__ Sm,
    const float* __restrict__ ksum, const float* __restrict__ kmsum,
    float* __restrict__ out)
{
  int bh = blockIdx.x; int b = bh >> 4, h = bh & 15;
  int l0 = blockIdx.y * 64;
  __shared__ float Gq[64][64], Gm[64][64];   // [dd][l]
  __shared__ float Ss[64][64], Sms[64][64];  // [dd][v]
  int t = threadIdx.x;

  // load S/Sm (4096 floats each)
  #pragma unroll
  for (int i = 0; i < 4; ++i) {
    int idx = t*4 + i*1024;
    *(float4*)&((float*)Ss)[idx]  = *(const float4*)&S [(size_t)bh*4096 + idx];
    *(float4*)&((float*)Sms)[idx] = *(const float4*)&Sm[(size_t)bh*4096 + idx];
  }

  // load q chunk, apply gfun, store transposed [dd][l]
  int lr = t >> 2, dq = (t & 3) * 16;
  const float4* qp = (const float4*)(q + (size_t)(b*L_ + l0 + lr)*E_ + h*64 + dq);
  float4 qv[4];
  #pragma unroll
  for (int j = 0; j < 4; ++j) qv[j] = qp[j];
  #pragma unroll
  for (int j = 0; j < 4; ++j) {
    float vals[4] = {qv[j].x, qv[j].y, qv[j].z, qv[j].w};
    #pragma unroll
    for (int jj = 0; jj < 4; ++jj) {
      int dd = dq + j*4 + jj;
      Gq[dd][lr] = gfun(vals[jj]);
      Gm[dd][lr] = gfun(-vals[jj]);
    }
  }
  __syncthreads();

  int tn = (t & 15) * 4, tm = (t >> 4) * 4;
  const float* ksp  = ksum  + bh*64;
  const float* kmsp = kmsum + bh*64;
  float acc[4][4] = {};
  float den[4] = {};
  #pragma unroll 8
  for (int kk = 0; kk < 64; ++kk) {
    float4 aq = *(const float4*)&Gq[kk][tm];
    float4 am = *(const float4*)&Gm[kk][tm];
    float4 bq = *(const float4*)&Ss[kk][tn];
    float4 bm = *(const float4*)&Sms[kk][tn];
    float ksv = ksp[kk], kmv = kmsp[kk];
    float aqv[4] = {aq.x, aq.y, aq.z, aq.w};
    float amv[4] = {am.x, am.y, am.z, am.w};
    float bqv[4] = {bq.x, bq.y, bq.z, bq.w};
    float bmv[4] = {bm.x, bm.y, bm.z, bm.w};
    #pragma unroll
    for (int i = 0; i < 4; ++i) {
      #pragma unroll
      for (int j = 0; j < 4; ++j)
        acc[i][j] += aqv[i]*bqv[j] + amv[i]*bmv[j];
      den[i] += aqv[i]*ksv + amv[i]*kmv;
    }
  }

  #pragma unroll
  for (int i = 0; i < 4; ++i) {
    float r = 1.0f / (den[i] + 1e-6f);
    float4 o;
    o.x = acc[i][0]*r; o.y = acc[i][1]*r; o.z = acc[i][2]*r; o.w = acc[i][3]*r;
    *(float4*)(out + (size_t)(b*L_ + l0 + tm + i)*E_ + h*64 + tn) = o;
  }
}

// ---------------------------------------------------------------------------
// Workspace layout (float units):
//   q     : 0          .. 16,777,216
//   k     : 16,777,216 .. 33,554,432
//   zeroed region (one hipMemsetAsync, 536,640 floats):
//     qg    : 33,554,432 (+4096)
//     S     : 33,558,528 (+262,144)
//     Sm    : 33,820,672 (+262,144)
//     ksum  : 34,082,816 (+4096)
//     kmsum : 34,086,912 (+4096)
//     denom : 34,091,008 (+64)
//   aexp  : 34,091,072 (+262,144)
//   Ah    : f-off 34,353,216, 33,554,432 bf16
//   Bt    : f-off 51,130,432,  6,291,456 bf16
//   end   : 54,276,160 floats = 217.1 MB
//   v lives in d_out (consumed by state_kernel, overwritten by out_kernel).
// ---------------------------------------------------------------------------
extern "C" void kernel_launch(void* const* d_in, const int* in_sizes, int n_in,
                              void* d_out, int out_size, void* d_ws, size_t ws_size,
                              hipStream_t stream) {
  const float* x  = (const float*)d_in[0];
  const float* Wq = (const float*)d_in[1];
  const float* bq = (const float*)d_in[2];
  const float* Wk = (const float*)d_in[3];
  const float* bk = (const float*)d_in[4];
  const float* Wv = (const float*)d_in[5];
  const float* bv = (const float*)d_in[6];
  float* out = (float*)d_out;
  float* ws  = (float*)d_ws;

  float* q     = ws;
  float* k     = ws + 16777216;
  float* qg    = ws + 33554432;
  float* S     = ws + 33558528;
  float* Sm    = ws + 33820672;
  float* ksum  = ws + 34082816;
  float* kmsum = ws + 34086912;
  float* denom = ws + 34091008;
  float* aexp  = ws + 34091072;
  unsigned short* Ah = (unsigned short*)(ws + 34353216);
  unsigned short* Bt = (unsigned short*)(ws + 51130432);
  float* v     = out;

  hipMemsetAsync(qg, 0, 536640 * sizeof(float), stream);

  split_x<<<16384, 256, 0, stream>>>(x, Ah);
  split_wT<<<dim3(32, 32, 3), 256, 0, stream>>>(Wq, Wk, Wv, Bt);
  qkv_mfma<<<dim3(8, 128, 3), 256, 0, stream>>>(Ah, Bt, bq, bk, bv, q, k, v);
  qglobal_kernel<<<dim3(B_*H_, 4), 256, 0, stream>>>(q, qg);
  alpha_p1<<<dim3(B_*H_, 8), 256, 0, stream>>>(k, qg, aexp, denom);
  state_kernel<<<dim3(B_*H_, 8), 256, 0, stream>>>(k, v, aexp, denom, S, Sm, ksum, kmsum);
  out_kernel<<<dim3(B_*H_, 64), 256, 0, stream>>>(q, S, Sm, ksum, kmsum, out);
}

// Round 4
// 896.759 us; speedup vs baseline: 2.2128x; 1.1747x over previous
//
#include <hip/hip_runtime.h>
#include <hip/hip_bf16.h>
#include <math.h>

// Problem constants
#define B_ 4
#define L_ 4096
#define E_ 1024
#define H_ 16
#define D_ 64
#define M_ (B_*L_)   // 16384 rows

typedef __attribute__((ext_vector_type(8))) short s8;     // 8 bf16 (4 VGPRs)
typedef __attribute__((ext_vector_type(4))) float f4;     // MFMA C/D

// g(x) = (softplus(5x)/5)^2.  Fast form: log1p(e^z) = log(1+e^z) via HW
// v_exp/v_log; clamp z<=60 so expf can't overflow (e^60=1.1e26 < fp32 max).
// abs error << 2^-11 everywhere (tiny-z case: sp^2 ~ e^{2z}, error ~1e-13).
__device__ __forceinline__ float gfun(float x) {
  float z = fminf(5.0f * x, 60.0f);
  float sp = 0.2f * __logf(1.0f + __expf(z));
  return sp * sp;
}

__device__ __forceinline__ unsigned short f2bf(float v) {
  __hip_bfloat16 h = __float2bfloat16(v);
  return *reinterpret_cast<unsigned short*>(&h);
}
__device__ __forceinline__ float bf2f(unsigned short u) {
  __hip_bfloat16 h = *reinterpret_cast<__hip_bfloat16*>(&u);
  return __bfloat162float(h);
}

// async global->LDS, 16 B per lane
__device__ __forceinline__ void gload16(const void* g, void* l) {
  __builtin_amdgcn_global_load_lds(
      (const __attribute__((address_space(1))) void*)g,
      (__attribute__((address_space(3))) void*)l, 16, 0, 0);
}

// ---------------------------------------------------------------------------
// Prep 1: split x (fp32 [16384,1024]) into bf16 hi|lo  -> Ah [16384, 2048]
// ---------------------------------------------------------------------------
__global__ __launch_bounds__(256) void split_x(
    const float* __restrict__ x, unsigned short* __restrict__ Ah)
{
  int idx = blockIdx.x * 256 + threadIdx.x;        // float4 index
  int m = idx >> 8, e = (idx & 255) * 4;
  float4 x4 = ((const float4*)x)[idx];
  float vv[4] = {x4.x, x4.y, x4.z, x4.w};
  ushort4 hi, lo;
  unsigned short h;
  h = f2bf(vv[0]); hi.x = h; lo.x = f2bf(vv[0] - bf2f(h));
  h = f2bf(vv[1]); hi.y = h; lo.y = f2bf(vv[1] - bf2f(h));
  h = f2bf(vv[2]); hi.z = h; lo.z = f2bf(vv[2] - bf2f(h));
  h = f2bf(vv[3]); hi.w = h; lo.w = f2bf(vv[3] - bf2f(h));
  *(ushort4*)&Ah[(size_t)m * 2048 + e]        = hi;
  *(ushort4*)&Ah[(size_t)m * 2048 + 1024 + e] = lo;
}

// ---------------------------------------------------------------------------
// Prep 2: transpose + split each W -> Bt[z] [1024, 2048] bf16 (hi | lo)
// ---------------------------------------------------------------------------
__global__ __launch_bounds__(256) void split_wT(
    const float* __restrict__ Wq, const float* __restrict__ Wk,
    const float* __restrict__ Wv, unsigned short* __restrict__ Bt)
{
  int z = blockIdx.z;
  const float* W = (z == 0) ? Wq : (z == 1) ? Wk : Wv;
  __shared__ float tile[32][33];
  int t = threadIdx.x;
  int tx = t & 31, ty = t >> 5;                    // ty 0..7
  int k0 = blockIdx.x * 32, n0 = blockIdx.y * 32;
  #pragma unroll
  for (int i = 0; i < 4; ++i)
    tile[ty + i*8][tx] = W[(size_t)(k0 + ty + i*8) * 1024 + n0 + tx];
  __syncthreads();
  unsigned short* Bz = Bt + (size_t)z * 2097152;
  #pragma unroll
  for (int i = 0; i < 4; ++i) {
    int n = n0 + ty + i*8, kk = k0 + tx;
    float v = tile[tx][ty + i*8];
    unsigned short h = f2bf(v);
    Bz[(size_t)n * 2048 + kk]        = h;
    Bz[(size_t)n * 2048 + 1024 + kk] = f2bf(v - bf2f(h));
  }
}

// ---------------------------------------------------------------------------
// Kernel 1: one QKV projection (split-bf16 MFMA, 3-product, K'=3072).
// One dispatch per {q,k,v} so tail kernels become visible in rocprof top-5.
// XCD swizzle: linear block id i -> xcd = i&7 (round-robin heuristic);
// m-block = xcd*16 + (i>>6), n-block = (i>>3)&7  =>  the 8 n-blocks sharing
// an A-tile land on ONE XCD's L2 (A-tile fetched ~1x instead of 8x).
// ---------------------------------------------------------------------------
__global__ __launch_bounds__(256) void qkv_mfma(
    const unsigned short* __restrict__ Ah, const unsigned short* __restrict__ Bz,
    const float* __restrict__ bias, float* __restrict__ out)
{
  __shared__ unsigned short As[4096];   // [128][32]
  __shared__ unsigned short Bs[4096];   // [128][32]

  const int t = threadIdx.x;
  const int li = blockIdx.y * 8 + blockIdx.x;   // 0..1023, dispatch-linear
  const int xc = li & 7, jj = li >> 3;
  const int bm = (xc * 16 + (jj >> 3)) * 128;
  const int bn = (jj & 7) * 128;

  const unsigned short* Ag0 = Ah + (size_t)(bm + (t >> 2)) * 2048 + (t & 3) * 8;
  const unsigned short* Bg0 = Bz + (size_t)(bn + (t >> 2)) * 2048 + (t & 3) * 8;
  unsigned short* Asd0 = &As[t * 8];
  unsigned short* Asd1 = &As[2048 + t * 8];
  unsigned short* Bsd0 = &Bs[t * 8];
  unsigned short* Bsd1 = &Bs[2048 + t * 8];

  const int lane = t & 63;
  const int wm = (t >> 6) & 1, wn = t >> 7;
  const int fr = lane & 15;
  const int fq = lane >> 4;

  f4 acc[4][4] = {};

  for (int k0 = 0; k0 < 3072; k0 += 32) {
    int seg = k0 >> 10, kk = k0 & 1023;
    int kA = kk + ((seg == 2) ? 1024 : 0);   // A: [hi, hi, lo]
    int kB = kk + ((seg == 1) ? 1024 : 0);   // B: [hi, lo, hi]
    gload16(Ag0 + kA, Asd0);
    gload16(Ag0 + 131072 + kA, Asd1);
    gload16(Bg0 + kB, Bsd0);
    gload16(Bg0 + 131072 + kB, Bsd1);
    __syncthreads();

    s8 a[4], b[4];
    #pragma unroll
    for (int i = 0; i < 4; ++i)
      a[i] = *(const s8*)&As[(wm * 64 + i * 16 + fr) * 32 + fq * 8];
    #pragma unroll
    for (int j = 0; j < 4; ++j)
      b[j] = *(const s8*)&Bs[(wn * 64 + j * 16 + fr) * 32 + fq * 8];
    #pragma unroll
    for (int i = 0; i < 4; ++i)
      #pragma unroll
      for (int j = 0; j < 4; ++j)
        acc[i][j] = __builtin_amdgcn_mfma_f32_16x16x32_bf16(a[i], b[j], acc[i][j], 0, 0, 0);
    __syncthreads();
  }

  float bv4[4];
  #pragma unroll
  for (int j = 0; j < 4; ++j) bv4[j] = bias[bn + wn * 64 + j * 16 + fr];
  #pragma unroll
  for (int i = 0; i < 4; ++i) {
    int mrow = bm + wm * 64 + i * 16 + fq * 4;
    #pragma unroll
    for (int j = 0; j < 4; ++j) {
      int ncol = bn + wn * 64 + j * 16 + fr;
      #pragma unroll
      for (int r = 0; r < 4; ++r)
        out[(size_t)(mrow + r) * E_ + ncol] = acc[i][j][r] + bv4[j];
    }
  }
}

// ---------------------------------------------------------------------------
// Kernel 2: q_global[b,h,d] = mean_l q[b,l,h,d] / sqrt(D)
// ---------------------------------------------------------------------------
__global__ __launch_bounds__(256) void qglobal_kernel(
    const float* __restrict__ q, float* __restrict__ qg)
{
  int bh = blockIdx.x;
  int b = bh >> 4, h = bh & 15;
  int t = threadIdx.x;
  int d = t & 63, c = t >> 6;
  int l0 = blockIdx.y * 1024 + c * 256;
  const float* base = q + (size_t)(b * L_ + l0) * E_ + h * 64 + d;
  float s = 0.f;
  #pragma unroll 8
  for (int i = 0; i < 256; ++i) s += base[(size_t)i * E_];
  __shared__ float red[256];
  red[t] = s;
  __syncthreads();
  if (t < 64) {
    float tot = red[d] + red[64+d] + red[128+d] + red[192+d];
    atomicAdd(&qg[bh*64 + d], tot * (1.0f / (L_ * 8.0f)));   // /L /sqrt(64)
  }
}

// ---------------------------------------------------------------------------
// Kernel 3: aexp[bh,l] = exp(qg . k[l]); denom[bh] += sum.
// Logits are O(0.05) by construction (qg is a mean/sqrt(D)) — no overflow.
// ---------------------------------------------------------------------------
__global__ __launch_bounds__(256) void alpha_p1(
    const float* __restrict__ k, const float* __restrict__ qg,
    float* __restrict__ aexp, float* __restrict__ denom)
{
  int bh = blockIdx.x; int b = bh >> 4, h = bh & 15;
  int l0 = blockIdx.y * 512;
  int t = threadIdx.x;
  __shared__ float qs[64];
  __shared__ float red[256];
  if (t < 64) qs[t] = qg[bh*64 + t];
  __syncthreads();

  float sum = 0.f;
  #pragma unroll
  for (int i = 0; i < 2; ++i) {
    int l = l0 + i*256 + t;
    const float4* kp = (const float4*)(k + (size_t)(b*L_ + l)*E_ + h*64);
    float dot = 0.f;
    #pragma unroll
    for (int j = 0; j < 16; ++j) {
      float4 kv = kp[j];
      dot += kv.x*qs[4*j] + kv.y*qs[4*j+1] + kv.z*qs[4*j+2] + kv.w*qs[4*j+3];
    }
    float e = __expf(dot);
    aexp[(size_t)bh * L_ + l] = e;
    sum += e;
  }
  red[t] = sum; __syncthreads();
  for (int s = 128; s > 0; s >>= 1) {
    if (t < s) red[t] += red[t+s];
    __syncthreads();
  }
  if (t == 0) atomicAdd(&denom[bh], red[0]);
}

// ---------------------------------------------------------------------------
// Kernel 4a: KV-state partials — NO atomics.  grid = (64 bh, 16 chunks of
// 256 l).  Each block writes its own partial S/Sm (64x64) + ksum/kmsum (64).
// ---------------------------------------------------------------------------
__global__ __launch_bounds__(256) void state_part(
    const float* __restrict__ k, const float* __restrict__ v,
    const float* __restrict__ aexp, const float* __restrict__ denom,
    float* __restrict__ Spart, float* __restrict__ SMpart,
    float* __restrict__ kpart, float* __restrict__ kmpart)
{
  int bh = blockIdx.x; int b = bh >> 4, h = bh & 15;
  int c = blockIdx.y;
  int l0 = c * 256;
  float scale = (float)L_ / denom[bh];
  __shared__ float gk[16][64], gmk[16][64], vt[16][64];
  int t = threadIdx.x;
  int d = t & 63, vb = (t >> 6) * 16;
  int lr = t >> 4, cc = (t & 15) * 4;
  float acc[16] = {}, accm[16] = {};
  float sgk = 0.f, sgmk = 0.f;

  for (int lt = 0; lt < 256; lt += 16) {
    int l = l0 + lt + lr;
    size_t off = (size_t)(b*L_ + l) * E_ + h*64 + cc;
    float4 k4 = *(const float4*)(k + off);
    float4 v4 = *(const float4*)(v + off);
    float av = aexp[(size_t)bh * L_ + l] * scale;
    __syncthreads();
    gk [lr][cc+0] = gfun( k4.x * av);  gmk[lr][cc+0] = gfun(-k4.x * av);
    gk [lr][cc+1] = gfun( k4.y * av);  gmk[lr][cc+1] = gfun(-k4.y * av);
    gk [lr][cc+2] = gfun( k4.z * av);  gmk[lr][cc+2] = gfun(-k4.z * av);
    gk [lr][cc+3] = gfun( k4.w * av);  gmk[lr][cc+3] = gfun(-k4.w * av);
    *(float4*)&vt[lr][cc] = v4;
    __syncthreads();
    #pragma unroll
    for (int l2 = 0; l2 < 16; ++l2) {
      float gkv = gk[l2][d], gmkv = gmk[l2][d];
      if (vb == 0) { sgk += gkv; sgmk += gmkv; }   // wave 0 only (uniform)
      #pragma unroll
      for (int jj = 0; jj < 4; ++jj) {
        float4 vv = *(float4*)&vt[l2][vb + jj*4];
        acc [jj*4+0] += gkv *vv.x; acc [jj*4+1] += gkv *vv.y;
        acc [jj*4+2] += gkv *vv.z; acc [jj*4+3] += gkv *vv.w;
        accm[jj*4+0] += gmkv*vv.x; accm[jj*4+1] += gmkv*vv.y;
        accm[jj*4+2] += gmkv*vv.z; accm[jj*4+3] += gmkv*vv.w;
      }
    }
  }

  size_t pb = ((size_t)(c*64 + bh)) * 4096 + (size_t)d * 64 + vb;
  #pragma unroll
  for (int j = 0; j < 16; j += 4) {
    float4 o, om;
    o.x  = acc [j]; o.y  = acc [j+1]; o.z  = acc [j+2]; o.w  = acc [j+3];
    om.x = accm[j]; om.y = accm[j+1]; om.z = accm[j+2]; om.w = accm[j+3];
    *(float4*)&Spart [pb + j] = o;
    *(float4*)&SMpart[pb + j] = om;
  }
  if (t < 64) {
    kpart [(c*64 + bh)*64 + d] = sgk;
    kmpart[(c*64 + bh)*64 + d] = sgmk;
  }
}

// ---------------------------------------------------------------------------
// Kernel 4b: reduce the 16 partials (deterministic, no atomics, no memset).
// grid = 64 (bh), 256 threads.
// ---------------------------------------------------------------------------
__global__ __launch_bounds__(256) void state_reduce(
    const float* __restrict__ Spart, const float* __restrict__ SMpart,
    const float* __restrict__ kpart, const float* __restrict__ kmpart,
    float* __restrict__ S, float* __restrict__ Sm,
    float* __restrict__ ksum, float* __restrict__ kmsum)
{
  int bh = blockIdx.x; int t = threadIdx.x;
  #pragma unroll
  for (int e = 0; e < 16; ++e) {
    int idx = e*256 + t;
    float s = 0.f, sm = 0.f;
    #pragma unroll
    for (int c = 0; c < 16; ++c) {
      s  += Spart [((size_t)(c*64 + bh))*4096 + idx];
      sm += SMpart[((size_t)(c*64 + bh))*4096 + idx];
    }
    S [(size_t)bh*4096 + idx] = s;
    Sm[(size_t)bh*4096 + idx] = sm;
  }
  if (t < 64) {
    float s = 0.f, sm = 0.f;
    #pragma unroll
    for (int c = 0; c < 16; ++c) {
      s  += kpart [(c*64 + bh)*64 + t];
      sm += kmpart[(c*64 + bh)*64 + t];
    }
    ksum [bh*64 + t] = s;
    kmsum[bh*64 + t] = sm;
  }
}

// ---------------------------------------------------------------------------
// Kernel 5: output, register-tiled fp32 GEMM microkernel (unroll 4 to cap
// VGPR pressure; 16 in-flight b128 instead of 32).
// ---------------------------------------------------------------------------
__global__ __launch_bounds__(256) void out_kernel(
    const float* __restrict__ q,
    const float* __restrict__ S, const float* __restrict__ Sm,
    const float* __restrict__ ksum, const float* __restrict__ kmsum,
    float* __restrict__ out)
{
  int bh = blockIdx.x; int b = bh >> 4, h = bh & 15;
  int l0 = blockIdx.y * 64;
  __shared__ float Gq[64][64], Gm[64][64];   // [dd][l]
  __shared__ float Ss[64][64], Sms[64][64];  // [dd][v]
  int t = threadIdx.x;

  #pragma unroll
  for (int i = 0; i < 4; ++i) {
    int idx = t*4 + i*1024;
    *(float4*)&((float*)Ss)[idx]  = *(const float4*)&S [(size_t)bh*4096 + idx];
    *(float4*)&((float*)Sms)[idx] = *(const float4*)&Sm[(size_t)bh*4096 + idx];
  }

  int lr = t >> 2, dq = (t & 3) * 16;
  const float4* qp = (const float4*)(q + (size_t)(b*L_ + l0 + lr)*E_ + h*64 + dq);
  float4 qv[4];
  #pragma unroll
  for (int j = 0; j < 4; ++j) qv[j] = qp[j];
  #pragma unroll
  for (int j = 0; j < 4; ++j) {
    float vals[4] = {qv[j].x, qv[j].y, qv[j].z, qv[j].w};
    #pragma unroll
    for (int jj = 0; jj < 4; ++jj) {
      int dd = dq + j*4 + jj;
      Gq[dd][lr] = gfun(vals[jj]);
      Gm[dd][lr] = gfun(-vals[jj]);
    }
  }
  __syncthreads();

  int tn = (t & 15) * 4, tm = (t >> 4) * 4;
  const float* ksp  = ksum  + bh*64;
  const float* kmsp = kmsum + bh*64;
  float acc[4][4] = {};
  float den[4] = {};
  #pragma unroll 4
  for (int kk = 0; kk < 64; ++kk) {
    float4 aq = *(const float4*)&Gq[kk][tm];
    float4 am = *(const float4*)&Gm[kk][tm];
    float4 bq = *(const float4*)&Ss[kk][tn];
    float4 bm = *(const float4*)&Sms[kk][tn];
    float ksv = ksp[kk], kmv = kmsp[kk];
    float aqv[4] = {aq.x, aq.y, aq.z, aq.w};
    float amv[4] = {am.x, am.y, am.z, am.w};
    float bqv[4] = {bq.x, bq.y, bq.z, bq.w};
    float bmv[4] = {bm.x, bm.y, bm.z, bm.w};
    #pragma unroll
    for (int i = 0; i < 4; ++i) {
      #pragma unroll
      for (int j = 0; j < 4; ++j)
        acc[i][j] += aqv[i]*bqv[j] + amv[i]*bmv[j];
      den[i] += aqv[i]*ksv + amv[i]*kmv;
    }
  }

  #pragma unroll
  for (int i = 0; i < 4; ++i) {
    float r = 1.0f / (den[i] + 1e-6f);
    float4 o;
    o.x = acc[i][0]*r; o.y = acc[i][1]*r; o.z = acc[i][2]*r; o.w = acc[i][3]*r;
    *(float4*)(out + (size_t)(b*L_ + l0 + tm + i)*E_ + h*64 + tn) = o;
  }
}

// ---------------------------------------------------------------------------
// Workspace layout (float units):
//   q      : 0          (+16,777,216)
//   k      : 16,777,216 (+16,777,216)
//   qg     : 33,554,432 (+4096)   \ zeroed by one hipMemsetAsync (4160 fl)
//   denom  : 33,558,528 (+64)     /
//   S      : 33,558,592 (+262,144)   (written fully by state_reduce)
//   Sm     : 33,820,736 (+262,144)
//   ksum   : 34,082,880 (+4096)
//   kmsum  : 34,086,976 (+4096)
//   aexp   : 34,091,072 (+262,144)
//   Ah     : f-off 34,353,216 (ushort 33,554,432 = 16,777,216 fl)
//   Bt     : f-off 51,130,432 (ushort  6,291,456 =  3,145,728 fl)
//   end 54,276,160 floats = 217.1 MB (same footprint as R3)
//   Spart/SMpart/kpart/kmpart OVERLAY the Ah region (Ah is dead after
//   qkv_mfma; every replay rewrites Ah via split_x first):
//     Spart  : 34,353,216 (+4,194,304)
//     SMpart : 38,547,520 (+4,194,304)
//     kpart  : 42,741,824 (+65,536)
//     kmpart : 42,807,360 (+65,536)     (ends 42,872,896 < 51,130,432 ✓)
//   v lives in d_out (consumed by state_part, overwritten by out_kernel).
// ---------------------------------------------------------------------------
extern "C" void kernel_launch(void* const* d_in, const int* in_sizes, int n_in,
                              void* d_out, int out_size, void* d_ws, size_t ws_size,
                              hipStream_t stream) {
  const float* x  = (const float*)d_in[0];
  const float* Wq = (const float*)d_in[1];
  const float* bq = (const float*)d_in[2];
  const float* Wk = (const float*)d_in[3];
  const float* bk = (const float*)d_in[4];
  const float* Wv = (const float*)d_in[5];
  const float* bv = (const float*)d_in[6];
  float* out = (float*)d_out;
  float* ws  = (float*)d_ws;

  float* q      = ws;
  float* k      = ws + 16777216;
  float* qg     = ws + 33554432;
  float* denom  = ws + 33558528;
  float* S      = ws + 33558592;
  float* Sm     = ws + 33820736;
  float* ksum   = ws + 34082880;
  float* kmsum  = ws + 34086976;
  float* aexp   = ws + 34091072;
  unsigned short* Ah = (unsigned short*)(ws + 34353216);
  unsigned short* Bt = (unsigned short*)(ws + 51130432);
  float* Spart  = ws + 34353216;   // overlays Ah (dead after qkv_mfma)
  float* SMpart = ws + 38547520;
  float* kpart  = ws + 42741824;
  float* kmpart = ws + 42807360;
  float* v      = out;

  hipMemsetAsync(qg, 0, 4160 * sizeof(float), stream);

  split_x<<<16384, 256, 0, stream>>>(x, Ah);
  split_wT<<<dim3(32, 32, 3), 256, 0, stream>>>(Wq, Wk, Wv, Bt);
  qkv_mfma<<<dim3(8, 128), 256, 0, stream>>>(Ah, Bt,           bq, q);
  qkv_mfma<<<dim3(8, 128), 256, 0, stream>>>(Ah, Bt + 2097152, bk, k);
  qkv_mfma<<<dim3(8, 128), 256, 0, stream>>>(Ah, Bt + 4194304, bv, v);
  qglobal_kernel<<<dim3(B_*H_, 4), 256, 0, stream>>>(q, qg);
  alpha_p1<<<dim3(B_*H_, 8), 256, 0, stream>>>(k, qg, aexp, denom);
  state_part<<<dim3(B_*H_, 16), 256, 0, stream>>>(k, v, aexp, denom,
                                                  Spart, SMpart, kpart, kmpart);
  state_reduce<<<B_*H_, 256, 0, stream>>>(Spart, SMpart, kpart, kmpart,
                                          S, Sm, ksum, kmsum);
  out_kernel<<<dim3(B_*H_, 64), 256, 0, stream>>>(q, S, Sm, ksum, kmsum, out);
}

// Round 5
// 761.340 us; speedup vs baseline: 2.6063x; 1.1779x over previous
//
#include <hip/hip_runtime.h>
#include <hip/hip_bf16.h>
#include <math.h>

// Problem constants
#define B_ 4
#define L_ 4096
#define E_ 1024
#define H_ 16
#define D_ 64
#define M_ (B_*L_)   // 16384 rows

typedef __attribute__((ext_vector_type(8))) short s8;     // 8 bf16 (4 VGPRs)
typedef __attribute__((ext_vector_type(4))) float f4;     // MFMA C/D

// g(x) = (softplus(5x)/5)^2 via HW v_exp/v_log; clamp z<=60 (no overflow).
__device__ __forceinline__ float gfun(float x) {
  float z = fminf(5.0f * x, 60.0f);
  float sp = 0.2f * __logf(1.0f + __expf(z));
  return sp * sp;
}

__device__ __forceinline__ unsigned short f2bf(float v) {
  __hip_bfloat16 h = __float2bfloat16(v);
  return *reinterpret_cast<unsigned short*>(&h);
}
__device__ __forceinline__ float bf2f(unsigned short u) {
  __hip_bfloat16 h = *reinterpret_cast<__hip_bfloat16*>(&u);
  return __bfloat162float(h);
}

// async global->LDS, 16 B per lane
__device__ __forceinline__ void gload16(const void* g, void* l) {
  __builtin_amdgcn_global_load_lds(
      (const __attribute__((address_space(1))) void*)g,
      (__attribute__((address_space(3))) void*)l, 16, 0, 0);
}

// ---------------------------------------------------------------------------
// Prep 1: split x into bf16 hi|lo -> Ah [16384,2048], AND accumulate per-b
// column sums (xsum[b][e]) for the q-global path.  grid 256 blocks x 256 thr;
// block = 64 rows of one b; thread = one float4 column group.
// ---------------------------------------------------------------------------
__global__ __launch_bounds__(256) void split_x(
    const float* __restrict__ x, unsigned short* __restrict__ Ah,
    float* __restrict__ xsum)
{
  int blk = blockIdx.x, t = threadIdx.x;
  int r0 = blk * 64, b = r0 >> 12;
  int c4 = t * 4;
  float4 cs = {0.f, 0.f, 0.f, 0.f};
  for (int r = 0; r < 64; ++r) {
    int row = r0 + r;
    float4 x4 = *(const float4*)(x + (size_t)row * E_ + c4);
    ushort4 hi, lo;
    unsigned short h;
    h = f2bf(x4.x); hi.x = h; lo.x = f2bf(x4.x - bf2f(h));
    h = f2bf(x4.y); hi.y = h; lo.y = f2bf(x4.y - bf2f(h));
    h = f2bf(x4.z); hi.z = h; lo.z = f2bf(x4.z - bf2f(h));
    h = f2bf(x4.w); hi.w = h; lo.w = f2bf(x4.w - bf2f(h));
    *(ushort4*)&Ah[(size_t)row * 2048 + c4]        = hi;
    *(ushort4*)&Ah[(size_t)row * 2048 + 1024 + c4] = lo;
    cs.x += x4.x; cs.y += x4.y; cs.z += x4.z; cs.w += x4.w;
  }
  atomicAdd(&xsum[b * E_ + c4 + 0], cs.x);
  atomicAdd(&xsum[b * E_ + c4 + 1], cs.y);
  atomicAdd(&xsum[b * E_ + c4 + 2], cs.z);
  atomicAdd(&xsum[b * E_ + c4 + 3], cs.w);
}

// ---------------------------------------------------------------------------
// Prep 2: transpose + split each W -> Bt[z] [1024,2048] bf16 (hi|lo).
// z==0 blocks also finish qg: qg[b][n] += (sum_k xsum[b][k]*Wq[k][n])/(L*8)
// (+ bq[n]/8 from the k0==0 blocks).  Wq tile already in LDS.
// ---------------------------------------------------------------------------
__global__ __launch_bounds__(256) void split_wT(
    const float* __restrict__ Wq, const float* __restrict__ Wk,
    const float* __restrict__ Wv, const float* __restrict__ bq,
    const float* __restrict__ xsum,
    unsigned short* __restrict__ Bt, float* __restrict__ qg)
{
  int z = blockIdx.z;
  const float* W = (z == 0) ? Wq : (z == 1) ? Wk : Wv;
  __shared__ float tile[32][33];
  int t = threadIdx.x;
  int tx = t & 31, ty = t >> 5;                    // ty 0..7
  int k0 = blockIdx.x * 32, n0 = blockIdx.y * 32;
  #pragma unroll
  for (int i = 0; i < 4; ++i)
    tile[ty + i*8][tx] = W[(size_t)(k0 + ty + i*8) * 1024 + n0 + tx];
  __syncthreads();
  unsigned short* Bz = Bt + (size_t)z * 2097152;
  #pragma unroll
  for (int i = 0; i < 4; ++i) {
    int n = n0 + ty + i*8, kk = k0 + tx;
    float v = tile[tx][ty + i*8];
    unsigned short h = f2bf(v);
    Bz[(size_t)n * 2048 + kk]        = h;
    Bz[(size_t)n * 2048 + 1024 + kk] = f2bf(v - bf2f(h));
  }
  if (z == 0 && t < 128) {
    int n = t & 31, b = t >> 5;
    float dot = 0.f;
    #pragma unroll
    for (int kk = 0; kk < 32; ++kk)
      dot += xsum[b * E_ + k0 + kk] * tile[kk][n];
    float val = dot * (1.0f / (L_ * 8.0f));
    if (k0 == 0) val += bq[n0 + n] * 0.125f;
    atomicAdd(&qg[b * E_ + n0 + n], val);
  }
}

// ---------------------------------------------------------------------------
// Kernel 1: fused QKV (split-bf16 MFMA, K'=3072), ONE dispatch (3072 blocks,
// tail-amortized).  XCD swizzle: li -> xcd = li&7; per-XCD order z-outer so
// one z's 8 B-tiles (4 MB) stay L2-resident while A streams.
// z==1 blocks run the alpha epilogue: each wave's C-tile holds 64 rows x one
// full head; logit = qg . k via 4-step fr-butterfly; aexp=exp(logit), denom+=.
// ---------------------------------------------------------------------------
__global__ __launch_bounds__(256) void qkv_mfma(
    const unsigned short* __restrict__ Ah, const unsigned short* __restrict__ Bt,
    const float* __restrict__ bq, const float* __restrict__ bk,
    const float* __restrict__ bv, const float* __restrict__ qg,
    float* __restrict__ aexp, float* __restrict__ denom,
    float* __restrict__ qo, float* __restrict__ ko, float* __restrict__ vo)
{
  __shared__ unsigned short As[4096];   // [128][32]
  __shared__ unsigned short Bs[4096];   // [128][32]

  const int t = threadIdx.x;
  const int li = (blockIdx.z * 128 + blockIdx.y) * 8 + blockIdx.x;  // 0..3071
  const int xc  = li & 7;
  const int jj  = li >> 3;      // 0..383 within XCD
  const int z   = jj >> 7;      // 0..2 (z-outer per XCD)
  const int rem = jj & 127;
  const int bn  = (rem & 7) * 128;
  const int bm  = (xc * 16 + (rem >> 3)) * 128;

  const float* bias = (z == 0) ? bq : (z == 1) ? bk : bv;
  float* out = (z == 0) ? qo : (z == 1) ? ko : vo;
  const unsigned short* Bz = Bt + (size_t)z * 2097152;

  const unsigned short* Ag0 = Ah + (size_t)(bm + (t >> 2)) * 2048 + (t & 3) * 8;
  const unsigned short* Bg0 = Bz + (size_t)(bn + (t >> 2)) * 2048 + (t & 3) * 8;
  unsigned short* Asd0 = &As[t * 8];
  unsigned short* Asd1 = &As[2048 + t * 8];
  unsigned short* Bsd0 = &Bs[t * 8];
  unsigned short* Bsd1 = &Bs[2048 + t * 8];

  const int lane = t & 63;
  const int wm = (t >> 6) & 1, wn = t >> 7;
  const int fr = lane & 15;
  const int fq = lane >> 4;

  f4 acc[4][4] = {};

  for (int k0 = 0; k0 < 3072; k0 += 32) {
    int seg = k0 >> 10, kk = k0 & 1023;
    int kA = kk + ((seg == 2) ? 1024 : 0);   // A: [hi, hi, lo]
    int kB = kk + ((seg == 1) ? 1024 : 0);   // B: [hi, lo, hi]
    gload16(Ag0 + kA, Asd0);
    gload16(Ag0 + 131072 + kA, Asd1);
    gload16(Bg0 + kB, Bsd0);
    gload16(Bg0 + 131072 + kB, Bsd1);
    __syncthreads();

    s8 a[4], b[4];
    #pragma unroll
    for (int i = 0; i < 4; ++i)
      a[i] = *(const s8*)&As[(wm * 64 + i * 16 + fr) * 32 + fq * 8];
    #pragma unroll
    for (int j = 0; j < 4; ++j)
      b[j] = *(const s8*)&Bs[(wn * 64 + j * 16 + fr) * 32 + fq * 8];
    #pragma unroll
    for (int i = 0; i < 4; ++i)
      #pragma unroll
      for (int j = 0; j < 4; ++j)
        acc[i][j] = __builtin_amdgcn_mfma_f32_16x16x32_bf16(a[i], b[j], acc[i][j], 0, 0, 0);
    __syncthreads();
  }

  float bv4[4];
  #pragma unroll
  for (int j = 0; j < 4; ++j) bv4[j] = bias[bn + wn * 64 + j * 16 + fr];
  #pragma unroll
  for (int i = 0; i < 4; ++i) {
    int mrow = bm + wm * 64 + i * 16 + fq * 4;
    #pragma unroll
    for (int j = 0; j < 4; ++j) {
      int ncol = bn + wn * 64 + j * 16 + fr;
      #pragma unroll
      for (int r = 0; r < 4; ++r)
        out[(size_t)(mrow + r) * E_ + ncol] = acc[i][j][r] + bv4[j];
    }
  }

  if (z == 1) {
    // alpha epilogue: logits for this wave's 64 rows x head (bn>>6)+wn
    int b_  = bm >> 12;
    int h   = (bn >> 6) + wn;
    int bh  = b_ * 16 + h;
    float qgv[4];
    #pragma unroll
    for (int j = 0; j < 4; ++j) qgv[j] = qg[bh * 64 + j * 16 + fr];
    float partial[4][4];
    #pragma unroll
    for (int i = 0; i < 4; ++i)
      #pragma unroll
      for (int r = 0; r < 4; ++r) {
        float p = 0.f;
        #pragma unroll
        for (int j = 0; j < 4; ++j)
          p += qgv[j] * (acc[i][j][r] + bv4[j]);
        p += __shfl_xor(p, 1);
        p += __shfl_xor(p, 2);
        p += __shfl_xor(p, 4);
        p += __shfl_xor(p, 8);
        partial[i][r] = p;
      }
    if (fr == 0) {
      int lbase = (bm & 4095) + wm * 64 + fq * 4;
      float s = 0.f;
      #pragma unroll
      for (int i = 0; i < 4; ++i)
        #pragma unroll
        for (int r = 0; r < 4; ++r) {
          float e = __expf(partial[i][r]);
          aexp[(size_t)bh * 4096 + lbase + i * 16 + r] = e;
          s += e;
        }
      atomicAdd(&denom[bh], s);
    }
  }
}

// ---------------------------------------------------------------------------
// Kernel 2: KV-state partials, no atomics.  grid (64 bh, 16 chunks of 256 l).
// 2 l-teams x (16 d-groups x 8 v-groups); 4d x 8v register tile per thread:
// per K-step 4 LDS b128 serve 64 FMAs (was 6 per 32).  32 partials.
// ---------------------------------------------------------------------------
__global__ __launch_bounds__(256) void state_part(
    const float* __restrict__ k, const float* __restrict__ v,
    const float* __restrict__ aexp, const float* __restrict__ denom,
    float* __restrict__ Spart, float* __restrict__ SMpart,
    float* __restrict__ kpart, float* __restrict__ kmpart)
{
  int bh = blockIdx.x; int b = bh >> 4, h = bh & 15;
  int c = blockIdx.y;
  int l0 = c * 256;
  float scale = (float)L_ / denom[bh];
  __shared__ float gk[16][64], gmk[16][64], vt[16][64];
  int t = threadIdx.x;
  int lr = t >> 4, cc = (t & 15) * 4;                   // staging role
  int vg = (t & 7) * 8, dg = ((t >> 3) & 15) * 4, team = t >> 7;
  float acc[4][8] = {}, accm[4][8] = {};
  float sgk[4] = {}, sgmk[4] = {};

  for (int lt = 0; lt < 256; lt += 16) {
    int l = l0 + lt + lr;
    size_t off = (size_t)(b*L_ + l) * E_ + h*64 + cc;
    float4 k4 = *(const float4*)(k + off);
    float4 v4 = *(const float4*)(v + off);
    float av = aexp[(size_t)bh * L_ + l] * scale;
    __syncthreads();
    float4 g4, m4;
    g4.x = gfun( k4.x*av); m4.x = gfun(-k4.x*av);
    g4.y = gfun( k4.y*av); m4.y = gfun(-k4.y*av);
    g4.z = gfun( k4.z*av); m4.z = gfun(-k4.z*av);
    g4.w = gfun( k4.w*av); m4.w = gfun(-k4.w*av);
    *(float4*)&gk [lr][cc] = g4;
    *(float4*)&gmk[lr][cc] = m4;
    *(float4*)&vt [lr][cc] = v4;
    __syncthreads();
    #pragma unroll
    for (int l2 = 0; l2 < 8; ++l2) {
      int ls = team * 8 + l2;
      float4 ga = *(float4*)&gk [ls][dg];
      float4 ma = *(float4*)&gmk[ls][dg];
      float4 vA = *(float4*)&vt [ls][vg];
      float4 vB = *(float4*)&vt [ls][vg + 4];
      float gv[4] = {ga.x, ga.y, ga.z, ga.w};
      float mv[4] = {ma.x, ma.y, ma.z, ma.w};
      float vv[8] = {vA.x, vA.y, vA.z, vA.w, vB.x, vB.y, vB.z, vB.w};
      if ((t & 7) == 0) {
        #pragma unroll
        for (int i = 0; i < 4; ++i) { sgk[i] += gv[i]; sgmk[i] += mv[i]; }
      }
      #pragma unroll
      for (int i = 0; i < 4; ++i)
        #pragma unroll
        for (int j = 0; j < 8; ++j) {
          acc [i][j] += gv[i] * vv[j];
          accm[i][j] += mv[i] * vv[j];
        }
    }
  }

  int p = c * 2 + team;                       // 0..31
  size_t pb = ((size_t)(p*64 + bh)) * 4096 + (size_t)dg * 64 + vg;
  #pragma unroll
  for (int i = 0; i < 4; ++i) {
    *(float4*)&Spart [pb + i*64]     = *(float4*)&acc [i][0];
    *(float4*)&Spart [pb + i*64 + 4] = *(float4*)&acc [i][4];
    *(float4*)&SMpart[pb + i*64]     = *(float4*)&accm[i][0];
    *(float4*)&SMpart[pb + i*64 + 4] = *(float4*)&accm[i][4];
  }
  if ((t & 7) == 0) {
    #pragma unroll
    for (int i = 0; i < 4; ++i) {
      kpart [(p*64 + bh)*64 + dg + i] = sgk[i];
      kmpart[(p*64 + bh)*64 + dg + i] = sgmk[i];
    }
  }
}

// ---------------------------------------------------------------------------
// Kernel 3: reduce 32 partials (deterministic).  grid (64 bh, 4 segs).
// ---------------------------------------------------------------------------
__global__ __launch_bounds__(256) void state_reduce(
    const float* __restrict__ Spart, const float* __restrict__ SMpart,
    const float* __restrict__ kpart, const float* __restrict__ kmpart,
    float* __restrict__ S, float* __restrict__ Sm,
    float* __restrict__ ksum, float* __restrict__ kmsum)
{
  int bh = blockIdx.x, seg = blockIdx.y, t = threadIdx.x;
  int idx = seg * 1024 + t * 4;
  float4 s = {0,0,0,0}, sm = {0,0,0,0};
  #pragma unroll
  for (int p = 0; p < 32; ++p) {
    float4 a = *(const float4*)&Spart [((size_t)(p*64 + bh))*4096 + idx];
    float4 c = *(const float4*)&SMpart[((size_t)(p*64 + bh))*4096 + idx];
    s.x += a.x; s.y += a.y; s.z += a.z; s.w += a.w;
    sm.x += c.x; sm.y += c.y; sm.z += c.z; sm.w += c.w;
  }
  *(float4*)&S [(size_t)bh*4096 + idx] = s;
  *(float4*)&Sm[(size_t)bh*4096 + idx] = sm;
  if (seg == 0 && t < 64) {
    float a = 0.f, c = 0.f;
    #pragma unroll
    for (int p = 0; p < 32; ++p) {
      a += kpart [(p*64 + bh)*64 + t];
      c += kmpart[(p*64 + bh)*64 + t];
    }
    ksum [bh*64 + t] = a;
    kmsum[bh*64 + t] = c;
  }
}

// ---------------------------------------------------------------------------
// Kernel 4: output.  128 threads: 16 l-groups x 8 v-groups, 4l x 8v tile
// -> per K-step 6 b128 serve 144 FMAs (was 4 per 40).  LDS 64 KB, 2 blk/CU.
// ---------------------------------------------------------------------------
__global__ __launch_bounds__(128) void out_kernel(
    const float* __restrict__ q,
    const float* __restrict__ S, const float* __restrict__ Sm,
    const float* __restrict__ ksum, const float* __restrict__ kmsum,
    float* __restrict__ out)
{
  int bh = blockIdx.x; int b = bh >> 4, h = bh & 15;
  int l0 = blockIdx.y * 64;
  __shared__ float Gq[64][64], Gm[64][64];   // [dd][l]
  __shared__ float Ss[64][64], Sms[64][64];  // [dd][v]
  int t = threadIdx.x;

  #pragma unroll
  for (int i = 0; i < 8; ++i) {
    int idx = t*4 + i*512;
    *(float4*)&((float*)Ss)[idx]  = *(const float4*)&S [(size_t)bh*4096 + idx];
    *(float4*)&((float*)Sms)[idx] = *(const float4*)&Sm[(size_t)bh*4096 + idx];
  }

  // q -> gfun -> transposed LDS.  lr=t>>1 (row), dq=(t&1)*32 (col half).
  int lr = t >> 1, dq = (t & 1) * 32;
  const float4* qp = (const float4*)(q + (size_t)(b*L_ + l0 + lr)*E_ + h*64 + dq);
  #pragma unroll
  for (int j = 0; j < 8; ++j) {
    float4 qv = qp[j];
    float vals[4] = {qv.x, qv.y, qv.z, qv.w};
    #pragma unroll
    for (int jj = 0; jj < 4; ++jj) {
      int dd = dq + j*4 + jj;
      Gq[dd][lr] = gfun(vals[jj]);
      Gm[dd][lr] = gfun(-vals[jj]);
    }
  }
  __syncthreads();

  int tn = (t & 7) * 8, tm = (t >> 3) * 4;
  const float* ksp  = ksum  + bh*64;
  const float* kmsp = kmsum + bh*64;
  float acc[4][8] = {};
  float den[4] = {};
  #pragma unroll 4
  for (int kk = 0; kk < 64; ++kk) {
    float4 ga = *(const float4*)&Gq[kk][tm];
    float4 ma = *(const float4*)&Gm[kk][tm];
    float4 s0 = *(const float4*)&Ss[kk][tn];
    float4 s1 = *(const float4*)&Ss[kk][tn + 4];
    float4 m0 = *(const float4*)&Sms[kk][tn];
    float4 m1 = *(const float4*)&Sms[kk][tn + 4];
    float ksv = ksp[kk], kmv = kmsp[kk];
    float gv[4] = {ga.x, ga.y, ga.z, ga.w};
    float mv[4] = {ma.x, ma.y, ma.z, ma.w};
    float sv[8] = {s0.x, s0.y, s0.z, s0.w, s1.x, s1.y, s1.z, s1.w};
    float smv[8] = {m0.x, m0.y, m0.z, m0.w, m1.x, m1.y, m1.z, m1.w};
    #pragma unroll
    for (int i = 0; i < 4; ++i) {
      #pragma unroll
      for (int j = 0; j < 8; ++j)
        acc[i][j] += gv[i]*sv[j] + mv[i]*smv[j];
      den[i] += gv[i]*ksv + mv[i]*kmv;
    }
  }

  #pragma unroll
  for (int i = 0; i < 4; ++i) {
    float r = 1.0f / (den[i] + 1e-6f);
    float4 o0, o1;
    o0.x = acc[i][0]*r; o0.y = acc[i][1]*r; o0.z = acc[i][2]*r; o0.w = acc[i][3]*r;
    o1.x = acc[i][4]*r; o1.y = acc[i][5]*r; o1.z = acc[i][6]*r; o1.w = acc[i][7]*r;
    size_t ro = (size_t)(b*L_ + l0 + tm + i)*E_ + h*64 + tn;
    *(float4*)(out + ro)     = o0;
    *(float4*)(out + ro + 4) = o1;
  }
}

// ---------------------------------------------------------------------------
// Workspace layout (float units):
//   q      : 0          (+16,777,216)
//   k      : 16,777,216 (+16,777,216)
//   qg     : 33,554,432 (+4096)  \
//   denom  : 33,558,528 (+64)     | zeroed by one hipMemsetAsync (8256 fl)
//   xsum   : 33,558,592 (+4096)  /
//   S      : 33,562,688 (+262,144)
//   Sm     : 33,824,832 (+262,144)
//   ksum   : 34,086,976 (+4096)
//   kmsum  : 34,091,072 (+4096)
//   aexp   : 34,095,168 (+262,144)
//   Ah     : f-off 34,357,312 (ushort 33,554,432 = 16,777,216 fl)
//   Bt     : f-off 51,134,528 (ushort  6,291,456 =  3,145,728 fl)
//   end 54,280,256 fl = 217.1 MB
//   Overlays (dead after qkv_mfma): Spart @34,357,312 (+8,388,608),
//   SMpart @42,745,920 (+8,388,608) [= Ah region exactly], kpart @51,134,528
//   (+131,072), kmpart @51,265,600 (+131,072) [inside Bt region].
//   v lives in d_out (consumed by state_part, overwritten by out_kernel).
// ---------------------------------------------------------------------------
extern "C" void kernel_launch(void* const* d_in, const int* in_sizes, int n_in,
                              void* d_out, int out_size, void* d_ws, size_t ws_size,
                              hipStream_t stream) {
  const float* x  = (const float*)d_in[0];
  const float* Wq = (const float*)d_in[1];
  const float* bq = (const float*)d_in[2];
  const float* Wk = (const float*)d_in[3];
  const float* bk = (const float*)d_in[4];
  const float* Wv = (const float*)d_in[5];
  const float* bv = (const float*)d_in[6];
  float* out = (float*)d_out;
  float* ws  = (float*)d_ws;

  float* q      = ws;
  float* k      = ws + 16777216;
  float* qg     = ws + 33554432;
  float* denom  = ws + 33558528;
  float* xsum   = ws + 33558592;
  float* S      = ws + 33562688;
  float* Sm     = ws + 33824832;
  float* ksum   = ws + 34086976;
  float* kmsum  = ws + 34091072;
  float* aexp   = ws + 34095168;
  unsigned short* Ah = (unsigned short*)(ws + 34357312);
  unsigned short* Bt = (unsigned short*)(ws + 51134528);
  float* Spart  = ws + 34357312;   // overlays Ah (dead after qkv_mfma)
  float* SMpart = ws + 42745920;
  float* kpart  = ws + 51134528;   // overlays Bt (dead after qkv_mfma)
  float* kmpart = ws + 51265600;
  float* v      = out;

  hipMemsetAsync(qg, 0, 8256 * sizeof(float), stream);

  split_x<<<256, 256, 0, stream>>>(x, Ah, xsum);
  split_wT<<<dim3(32, 32, 3), 256, 0, stream>>>(Wq, Wk, Wv, bq, xsum, Bt, qg);
  qkv_mfma<<<dim3(8, 128, 3), 256, 0, stream>>>(Ah, Bt, bq, bk, bv, qg,
                                                aexp, denom, q, k, v);
  state_part<<<dim3(B_*H_, 16), 256, 0, stream>>>(k, v, aexp, denom,
                                                  Spart, SMpart, kpart, kmpart);
  state_reduce<<<dim3(B_*H_, 4), 256, 0, stream>>>(Spart, SMpart, kpart, kmpart,
                                                   S, Sm, ksum, kmsum);
  out_kernel<<<dim3(B_*H_, 64), 128, 0, stream>>>(q, S, Sm, ksum, kmsum, out);
}